// Round 9
// baseline (3752.541 us; speedup 1.0000x reference)
//
#include <hip/hip_runtime.h>
#include <math.h>

#define TT 2048      // B*S tokens
#define BB 2
#define SS 1024
#define DD 768
#define HH 12
#define FF 3072
#define EE 8
#define VV 32000
#define NLAYER 2
#define QBLK 8

typedef __attribute__((ext_vector_type(8))) short bf16x8;
typedef __attribute__((ext_vector_type(4))) float f32x4;

#define GL16(ldst, gsrc) __builtin_amdgcn_global_load_lds( \
    (const __attribute__((address_space(1))) void*)(gsrc), \
    (__attribute__((address_space(3))) void*)(ldst), 16, 0, 0)

static __device__ __forceinline__ unsigned short f2b(float f) {
  unsigned u = __float_as_uint(f);
  unsigned r = (u + 0x7fffu + ((u >> 16) & 1u)) >> 16;
  return (unsigned short)r;
}
static __device__ __forceinline__ unsigned int pk2(float a, float b) {
  return (unsigned int)f2b(a) | ((unsigned int)f2b(b) << 16);
}

// ---------------- embedding: x = emb[tok] + pos ----------------
__global__ __launch_bounds__(256) void k_embed(const int* __restrict__ tok,
    const float* __restrict__ emb, const float* __restrict__ pos,
    float* __restrict__ x) {
  int t = blockIdx.x;
  int s = t & (SS - 1);
  int tk = tok[t];
  const float* er = emb + (size_t)tk * DD;
  const float* pr = pos + (size_t)s * DD;
  float* xr = x + (size_t)t * DD;
  for (int d = threadIdx.x; d < DD; d += 256)
    xr[d] = er[d] + pr[d];
}

// ------------- rmsnorm: writes f32 out AND bf16 out -------------
__global__ __launch_bounds__(256) void k_rmsnorm(const float* __restrict__ x,
    const float* __restrict__ w, float* __restrict__ out,
    unsigned short* __restrict__ outb) {
  int t = blockIdx.x;
  const float* xr = x + (size_t)t * DD;
  int tid = threadIdx.x;
  float v0 = xr[tid], v1 = xr[tid + 256], v2 = xr[tid + 512];
  float ss = v0 * v0 + v1 * v1 + v2 * v2;
  for (int off = 32; off > 0; off >>= 1) ss += __shfl_down(ss, off, 64);
  __shared__ float ps[4];
  int wid = tid >> 6, lane = tid & 63;
  if (lane == 0) ps[wid] = ss;
  __syncthreads();
  float r = rsqrtf((ps[0] + ps[1] + ps[2] + ps[3]) * (1.0f / DD) + 1e-6f);
  float* orow = out + (size_t)t * DD;
  unsigned short* brow = outb + (size_t)t * DD;
  float o0 = v0 * r * w[tid], o1 = v1 * r * w[tid + 256], o2 = v2 * r * w[tid + 512];
  orow[tid] = o0; orow[tid + 256] = o1; orow[tid + 512] = o2;
  brow[tid] = f2b(o0); brow[tid + 256] = f2b(o1); brow[tid + 512] = f2b(o2);
}

// ------------- transpose+convert: f32 [R][C] -> bf16 [C][R] -------------
__global__ __launch_bounds__(256) void k_tcvt(const float* __restrict__ src,
    unsigned short* __restrict__ dst, int R, int C, size_t srcZ, size_t dstZ) {
  src += (size_t)blockIdx.z * srcZ;
  dst += (size_t)blockIdx.z * dstZ;
  __shared__ unsigned short tile[32][40];
  int t = threadIdx.x;
  int r = t >> 3, c4 = (t & 7) * 4;
  int r0 = blockIdx.y * 32, c0 = blockIdx.x * 32;
  float4 v = *(const float4*)(src + (size_t)(r0 + r) * C + c0 + c4);
  tile[r][c4 + 0] = f2b(v.x); tile[r][c4 + 1] = f2b(v.y);
  tile[r][c4 + 2] = f2b(v.z); tile[r][c4 + 3] = f2b(v.w);
  __syncthreads();
  int cc = t >> 3, r4 = (t & 7) * 4;
  ushort4 o;
  o.x = tile[r4 + 0][cc]; o.y = tile[r4 + 1][cc];
  o.z = tile[r4 + 2][cc]; o.w = tile[r4 + 3][cc];
  *(ushort4*)(dst + (size_t)(c0 + cc) * R + r0 + r4) = o;
}

// ------------- straight convert f32 -> bf16 (same layout) -------------
__global__ __launch_bounds__(256) void k_cvt(const float* __restrict__ src,
    unsigned short* __restrict__ dst) {
  size_t i = ((size_t)blockIdx.x * 256 + threadIdx.x) * 8;
  float4 a = *(const float4*)(src + i);
  float4 b = *(const float4*)(src + i + 4);
  ushort4 o0, o1;
  o0.x = f2b(a.x); o0.y = f2b(a.y); o0.z = f2b(a.z); o0.w = f2b(a.w);
  o1.x = f2b(b.x); o1.y = f2b(b.y); o1.z = f2b(b.z); o1.w = f2b(b.w);
  *(ushort4*)(dst + i) = o0;
  *(ushort4*)(dst + i + 4) = o1;
}

// ======== f32 split-K 128x128 dense GEMM (QKV / O-proj), R8-proven ========
__global__ __launch_bounds__(256) void k_skf32(
    const float* __restrict__ A, const float* __restrict__ W0,
    const float* __restrict__ W1, const float* __restrict__ W2,
    float* __restrict__ part, int M, int Ntot, int Nthird, int K, int KC,
    int nsplit, int prows) {
  int s = blockIdx.z;
  int tpn = Nthird >> 7;
  int sel = blockIdx.x / tpn;
  int n0 = (blockIdx.x - sel * tpn) * 128;
  const float* W = sel == 0 ? W0 : sel == 1 ? W1 : W2;
  int m0 = blockIdx.y * 128;
  int kbase = s * KC;

  __shared__ float As[16][132];   // k-major: As[k][m]
  __shared__ float Bs[16][132];
  int tid = threadIdx.x;
  int tx = tid & 15, ty = tid >> 4;
  int ra = tid >> 1, ka0 = (tid & 1) * 8;
  int kb = tid >> 4, nb0 = (tid & 15) * 8;
  const float* Arow = A + (size_t)(m0 + ra) * K + kbase;
  float acc[8][8] = {};

  float4 av0 = *(const float4*)(Arow + ka0);
  float4 av1 = *(const float4*)(Arow + ka0 + 4);
  float4 bv0, bv1;
  {
    const float* Wrow = W + (size_t)(kbase + kb) * Nthird + n0 + nb0;
    bv0 = *(const float4*)(Wrow);
    bv1 = *(const float4*)(Wrow + 4);
  }

  for (int k0 = 0; k0 < KC; k0 += 16) {
    As[ka0 + 0][ra] = av0.x; As[ka0 + 1][ra] = av0.y;
    As[ka0 + 2][ra] = av0.z; As[ka0 + 3][ra] = av0.w;
    As[ka0 + 4][ra] = av1.x; As[ka0 + 5][ra] = av1.y;
    As[ka0 + 6][ra] = av1.z; As[ka0 + 7][ra] = av1.w;
    *(float4*)&Bs[kb][nb0] = bv0;
    *(float4*)&Bs[kb][nb0 + 4] = bv1;
    __syncthreads();
    float4 nav0 = make_float4(0.f, 0.f, 0.f, 0.f), nav1 = nav0, nbv0 = nav0, nbv1 = nav0;
    if (k0 + 16 < KC) {
      nav0 = *(const float4*)(Arow + k0 + 16 + ka0);
      nav1 = *(const float4*)(Arow + k0 + 16 + ka0 + 4);
      const float* Wn = W + (size_t)(kbase + k0 + 16 + kb) * Nthird + n0 + nb0;
      nbv0 = *(const float4*)(Wn);
      nbv1 = *(const float4*)(Wn + 4);
    }
#pragma unroll
    for (int kk = 0; kk < 16; kk++) {
      float4 a0 = *(const float4*)&As[kk][ty * 8];
      float4 a1 = *(const float4*)&As[kk][ty * 8 + 4];
      float4 b0 = *(const float4*)&Bs[kk][tx * 8];
      float4 b1 = *(const float4*)&Bs[kk][tx * 8 + 4];
      float a[8] = {a0.x, a0.y, a0.z, a0.w, a1.x, a1.y, a1.z, a1.w};
      float b[8] = {b0.x, b0.y, b0.z, b0.w, b1.x, b1.y, b1.z, b1.w};
#pragma unroll
      for (int i = 0; i < 8; i++) {
#pragma unroll
        for (int j = 0; j < 8; j++) acc[i][j] = fmaf(a[i], b[j], acc[i][j]);
      }
    }
    __syncthreads();
    av0 = nav0; av1 = nav1; bv0 = nbv0; bv1 = nbv1;
  }
#pragma unroll
  for (int i = 0; i < 8; i++) {
    int m = m0 + ty * 8 + i;
    size_t prow = (size_t)s * M + m;
    float* orow = part + prow * Ntot + sel * Nthird;
#pragma unroll
    for (int j = 0; j < 8; j++)
      orow[n0 + tx * 8 + j] = acc[i][j];
  }
}

// ======== f32 expert FFN1, 64x256 tile, 8x16 microtile (gather+gelu) ========
__global__ __launch_bounds__(128) void k_e1w(const float* __restrict__ h,
    const float* __restrict__ w1, const float* __restrict__ b1,
    const int* __restrict__ gtok, const int* __restrict__ counts,
    const int* __restrict__ bases, float* __restrict__ gh1) {
  int e = blockIdx.z;
  int cnt = counts[e];
  int m0 = blockIdx.y * 64;
  if (m0 >= cnt) return;
  int base = bases[e];
  int n0 = blockIdx.x * 256;
  const float* W = w1 + (size_t)e * DD * FF;
  __shared__ float As[16][68];    // k-major: As[k][m]
  __shared__ float Bs[16][272];   // group g (16 floats) at offset g*17
  int tid = threadIdx.x;
  int tx = tid & 15, ty = tid >> 4;         // ty 0..7
  int ra = tid >> 1, ka0 = (tid & 1) * 8;   // ra 0..63
  int kb = tid >> 3, nb0 = (tid & 7) * 32;  // kb 0..15
  int g0 = (tid & 7) * 2;
  float* bw0 = &Bs[kb][g0 * 17];
  float* bw1 = &Bs[kb][(g0 + 1) * 17];
  int tok = (m0 + ra < cnt) ? gtok[base + m0 + ra] : -1;
  const float* Arow = h + (size_t)(tok < 0 ? 0 : tok) * DD;
  float acc[8][16] = {};
  for (int k0 = 0; k0 < DD; k0 += 16) {
    float4 av0 = make_float4(0.f, 0.f, 0.f, 0.f), av1 = av0;
    if (tok >= 0) {
      av0 = *(const float4*)(Arow + k0 + ka0);
      av1 = *(const float4*)(Arow + k0 + ka0 + 4);
    }
    As[ka0 + 0][ra] = av0.x; As[ka0 + 1][ra] = av0.y;
    As[ka0 + 2][ra] = av0.z; As[ka0 + 3][ra] = av0.w;
    As[ka0 + 4][ra] = av1.x; As[ka0 + 5][ra] = av1.y;
    As[ka0 + 6][ra] = av1.z; As[ka0 + 7][ra] = av1.w;
    const float* Wr = W + (size_t)(k0 + kb) * FF + n0 + nb0;
    *(float4*)(bw0 + 0)  = *(const float4*)(Wr + 0);
    *(float4*)(bw0 + 4)  = *(const float4*)(Wr + 4);
    *(float4*)(bw0 + 8)  = *(const float4*)(Wr + 8);
    *(float4*)(bw0 + 12) = *(const float4*)(Wr + 12);
    *(float4*)(bw1 + 0)  = *(const float4*)(Wr + 16);
    *(float4*)(bw1 + 4)  = *(const float4*)(Wr + 20);
    *(float4*)(bw1 + 8)  = *(const float4*)(Wr + 24);
    *(float4*)(bw1 + 12) = *(const float4*)(Wr + 28);
    __syncthreads();
#pragma unroll
    for (int kk = 0; kk < 16; kk++) {
      float4 a0 = *(const float4*)&As[kk][ty * 8];
      float4 a1 = *(const float4*)&As[kk][ty * 8 + 4];
      const float* bp = &Bs[kk][tx * 17];
      float4 b0 = *(const float4*)(bp);
      float4 b1 = *(const float4*)(bp + 4);
      float4 b2 = *(const float4*)(bp + 8);
      float4 b3 = *(const float4*)(bp + 12);
      float a[8] = {a0.x, a0.y, a0.z, a0.w, a1.x, a1.y, a1.z, a1.w};
      float b[16] = {b0.x, b0.y, b0.z, b0.w, b1.x, b1.y, b1.z, b1.w,
                     b2.x, b2.y, b2.z, b2.w, b3.x, b3.y, b3.z, b3.w};
#pragma unroll
      for (int i = 0; i < 8; i++) {
#pragma unroll
        for (int j = 0; j < 16; j++) acc[i][j] = fmaf(a[i], b[j], acc[i][j]);
      }
    }
    __syncthreads();
  }
#pragma unroll
  for (int i = 0; i < 8; i++) {
    int m = m0 + ty * 8 + i;
    if (m >= cnt) continue;
    float* orow = gh1 + (size_t)(base + m) * FF;
#pragma unroll
    for (int j = 0; j < 16; j++) {
      int n = n0 + tx * 16 + j;
      float vv = acc[i][j] + b1[e * FF + n];
      orow[n] = 0.5f * vv * (1.f + erff(vv * 0.70710678118654752f));
    }
  }
}

// ======== f32 expert FFN2, 64x256 tile, 8x16 microtile, split-K=4 ========
__global__ __launch_bounds__(128) void k_e2w(const float* __restrict__ gh1,
    const float* __restrict__ w2, const int* __restrict__ counts,
    const int* __restrict__ bases, float* __restrict__ part) {
  int z = blockIdx.z;
  int s = z & 3, e = z >> 2;
  int cnt = counts[e];
  int m0 = blockIdx.y * 64;
  if (m0 >= cnt) return;
  int base = bases[e];
  int n0 = blockIdx.x * 256;
  int kbase = s * 768;
  const float* W = w2 + (size_t)e * FF * DD;
  __shared__ float As[16][68];
  __shared__ float Bs[16][272];
  int tid = threadIdx.x;
  int tx = tid & 15, ty = tid >> 4;
  int ra = tid >> 1, ka0 = (tid & 1) * 8;
  int kb = tid >> 3, nb0 = (tid & 7) * 32;
  int g0 = (tid & 7) * 2;
  float* bw0 = &Bs[kb][g0 * 17];
  float* bw1 = &Bs[kb][(g0 + 1) * 17];
  bool arow_ok = (m0 + ra < cnt);
  const float* Arow = gh1 + (size_t)(base + (arow_ok ? m0 + ra : 0)) * FF + kbase;
  float acc[8][16] = {};
  for (int k0 = 0; k0 < 768; k0 += 16) {
    float4 av0 = make_float4(0.f, 0.f, 0.f, 0.f), av1 = av0;
    if (arow_ok) {
      av0 = *(const float4*)(Arow + k0 + ka0);
      av1 = *(const float4*)(Arow + k0 + ka0 + 4);
    }
    As[ka0 + 0][ra] = av0.x; As[ka0 + 1][ra] = av0.y;
    As[ka0 + 2][ra] = av0.z; As[ka0 + 3][ra] = av0.w;
    As[ka0 + 4][ra] = av1.x; As[ka0 + 5][ra] = av1.y;
    As[ka0 + 6][ra] = av1.z; As[ka0 + 7][ra] = av1.w;
    const float* Wr = W + (size_t)(kbase + k0 + kb) * DD + n0 + nb0;
    *(float4*)(bw0 + 0)  = *(const float4*)(Wr + 0);
    *(float4*)(bw0 + 4)  = *(const float4*)(Wr + 4);
    *(float4*)(bw0 + 8)  = *(const float4*)(Wr + 8);
    *(float4*)(bw0 + 12) = *(const float4*)(Wr + 12);
    *(float4*)(bw1 + 0)  = *(const float4*)(Wr + 16);
    *(float4*)(bw1 + 4)  = *(const float4*)(Wr + 20);
    *(float4*)(bw1 + 8)  = *(const float4*)(Wr + 24);
    *(float4*)(bw1 + 12) = *(const float4*)(Wr + 28);
    __syncthreads();
#pragma unroll
    for (int kk = 0; kk < 16; kk++) {
      float4 a0 = *(const float4*)&As[kk][ty * 8];
      float4 a1 = *(const float4*)&As[kk][ty * 8 + 4];
      const float* bp = &Bs[kk][tx * 17];
      float4 b0 = *(const float4*)(bp);
      float4 b1 = *(const float4*)(bp + 4);
      float4 b2 = *(const float4*)(bp + 8);
      float4 b3 = *(const float4*)(bp + 12);
      float a[8] = {a0.x, a0.y, a0.z, a0.w, a1.x, a1.y, a1.z, a1.w};
      float b[16] = {b0.x, b0.y, b0.z, b0.w, b1.x, b1.y, b1.z, b1.w,
                     b2.x, b2.y, b2.z, b2.w, b3.x, b3.y, b3.z, b3.w};
#pragma unroll
      for (int i = 0; i < 8; i++) {
#pragma unroll
        for (int j = 0; j < 16; j++) acc[i][j] = fmaf(a[i], b[j], acc[i][j]);
      }
    }
    __syncthreads();
  }
#pragma unroll
  for (int i = 0; i < 8; i++) {
    int m = m0 + ty * 8 + i;
    if (m >= cnt) continue;
    float* orow = part + ((size_t)s * 4096 + base + m) * DD;
#pragma unroll
    for (int j = 0; j < 16; j++)
      orow[n0 + tx * 16 + j] = acc[i][j];
  }
}

// ---- QKV reduce: q/k/v = part0+part1 + bias ----
__global__ __launch_bounds__(256) void k_qkvred(const float* __restrict__ part,
    const float* __restrict__ bq, const float* __restrict__ bk,
    const float* __restrict__ bv, float* __restrict__ qb,
    float* __restrict__ kb, float* __restrict__ vb) {
  int t = blockIdx.x;
  for (int c = threadIdx.x; c < 2304; c += 256) {
    float v = part[(size_t)t * 2304 + c] + part[((size_t)TT + t) * 2304 + c];
    if (c < 768)       qb[(size_t)t * DD + c] = v + bq[c];
    else if (c < 1536) kb[(size_t)t * DD + c - 768] = v + bk[c - 768];
    else               vb[(size_t)t * DD + c - 1536] = v + bv[c - 1536];
  }
}

// ---- O-proj reduce: x += sum(part[0..3]) + bo ----
__global__ __launch_bounds__(256) void k_ored(const float* __restrict__ part,
    const float* __restrict__ bo, float* __restrict__ x) {
  int t = blockIdx.x;
  for (int d = threadIdx.x; d < DD; d += 256) {
    float v = part[(size_t)t * DD + d]
            + part[((size_t)TT + t) * DD + d]
            + part[((size_t)2 * TT + t) * DD + d]
            + part[((size_t)3 * TT + t) * DD + d];
    x[(size_t)t * DD + d] += v + bo[d];
  }
}

// ---- expert2 reduce + gate-weighted scatter: x += w*(sum(part)+b2) ----
__global__ __launch_bounds__(256) void k_e2red(const float* __restrict__ part,
    const int* __restrict__ rows, const int* __restrict__ tidx,
    const float* __restrict__ tw, const float* __restrict__ b2,
    float* __restrict__ x) {
  int t = blockIdx.x;
  int r0 = rows[t * 2], r1 = rows[t * 2 + 1];
  int e0 = tidx[t * 2], e1 = tidx[t * 2 + 1];
  float w0 = tw[t * 2], w1 = tw[t * 2 + 1];
  for (int d = threadIdx.x; d < DD; d += 256) {
    float v0 = part[(size_t)r0 * DD + d]
             + part[((size_t)4096 + r0) * DD + d]
             + part[((size_t)8192 + r0) * DD + d]
             + part[((size_t)12288 + r0) * DD + d] + b2[e0 * DD + d];
    float v1 = part[(size_t)r1 * DD + d]
             + part[((size_t)4096 + r1) * DD + d]
             + part[((size_t)8192 + r1) * DD + d]
             + part[((size_t)12288 + r1) * DD + d] + b2[e1 * DD + d];
    x[(size_t)t * DD + d] += w0 * v0 + w1 * v1;
  }
}

// ---------------- attention (f32, separate q/k/v) ----------------
__global__ __launch_bounds__(256) void k_attn(const float* __restrict__ q,
    const float* __restrict__ k, const float* __restrict__ v, float* __restrict__ ao) {
  int b = blockIdx.z, hh = blockIdx.y, q0 = blockIdx.x * QBLK;
  __shared__ float qs[QBLK][64];
  __shared__ float sc[QBLK][SS];
  __shared__ float red[QBLK][8];
  int tid = threadIdx.x;
  const size_t hoff = (size_t)b * SS * DD + (size_t)hh * 64;
  for (int i = tid; i < QBLK * 64; i += 256) {
    int qi = i >> 6, d = i & 63;
    qs[qi][d] = q[hoff + (size_t)(q0 + qi) * DD + d];
  }
  __syncthreads();
  int kmax = q0 + QBLK;
  for (int j = tid; j < kmax; j += 256) {
    const float* kr = k + hoff + (size_t)j * DD;
    float p[QBLK];
#pragma unroll
    for (int qi = 0; qi < QBLK; qi++) p[qi] = 0.f;
#pragma unroll 4
    for (int c = 0; c < 16; c++) {
      float4 kv = *(const float4*)(kr + c * 4);
#pragma unroll
      for (int qi = 0; qi < QBLK; qi++)
        p[qi] += qs[qi][c * 4] * kv.x + qs[qi][c * 4 + 1] * kv.y +
                 qs[qi][c * 4 + 2] * kv.z + qs[qi][c * 4 + 3] * kv.w;
    }
#pragma unroll
    for (int qi = 0; qi < QBLK; qi++)
      sc[qi][j] = (j <= q0 + qi) ? p[qi] * 0.125f : -1e30f;
  }
  __syncthreads();
  int wid = tid >> 6, lane = tid & 63;
#pragma unroll
  for (int qi = 0; qi < QBLK; qi++) {
    float mx = -1e30f;
    for (int j = tid; j < kmax; j += 256) mx = fmaxf(mx, sc[qi][j]);
    for (int off = 32; off > 0; off >>= 1) mx = fmaxf(mx, __shfl_down(mx, off, 64));
    if (lane == 0) red[qi][wid] = mx;
  }
  __syncthreads();
#pragma unroll
  for (int qi = 0; qi < QBLK; qi++) {
    float mx = fmaxf(fmaxf(red[qi][0], red[qi][1]), fmaxf(red[qi][2], red[qi][3]));
    float s = 0.f;
    for (int j = tid; j < kmax; j += 256) {
      float e = __expf(sc[qi][j] - mx);
      sc[qi][j] = e;
      s += e;
    }
    for (int off = 32; off > 0; off >>= 1) s += __shfl_down(s, off, 64);
    if (lane == 0) red[qi][4 + wid] = s;
  }
  __syncthreads();
  int d = tid & 63, g = tid >> 6;
  for (int qi = g; qi < QBLK; qi += 4) {
    float inv = 1.f / (red[qi][4] + red[qi][5] + red[qi][6] + red[qi][7]);
    int jend = q0 + qi + 1;
    const float* vp = v + hoff + d;
    float a0 = 0.f, a1 = 0.f, a2 = 0.f, a3 = 0.f;
    int j = 0;
    for (; j + 4 <= jend; j += 4) {
      a0 = fmaf(sc[qi][j],     vp[(size_t)j * DD], a0);
      a1 = fmaf(sc[qi][j + 1], vp[(size_t)(j + 1) * DD], a1);
      a2 = fmaf(sc[qi][j + 2], vp[(size_t)(j + 2) * DD], a2);
      a3 = fmaf(sc[qi][j + 3], vp[(size_t)(j + 3) * DD], a3);
    }
    for (; j < jend; j++) a0 = fmaf(sc[qi][j], vp[(size_t)j * DD], a0);
    float acc = (a0 + a2) + (a1 + a3);
    ao[hoff + (size_t)(q0 + qi) * DD + d] = acc * inv;
  }
}

// ---------------- gate logits ----------------
__global__ __launch_bounds__(256) void k_gate(const float* __restrict__ h,
    const float* __restrict__ gw, const float* __restrict__ gb,
    float* __restrict__ glog) {
  __shared__ float hr[DD];
  int t = blockIdx.x;
  for (int d = threadIdx.x; d < DD; d += 256) hr[d] = h[(size_t)t * DD + d];
  __syncthreads();
  int e = threadIdx.x >> 5, j = threadIdx.x & 31;
  float s = 0.f;
  for (int d = j; d < DD; d += 32) s += hr[d] * gw[d * EE + e];
  for (int off = 16; off > 0; off >>= 1) s += __shfl_down(s, off, 32);
  if (j == 0) glog[t * EE + e] = s + gb[e];
}

// ---------------- router ----------------
__global__ void k_zero(int* counts, int* cursor) {
  int i = threadIdx.x;
  if (i < EE) { counts[i] = 0; cursor[i] = 0; }
}

__global__ void k_router(const float* __restrict__ glog, int* __restrict__ tidx,
    float* __restrict__ tw, int* __restrict__ counts) {
  int t = blockIdx.x * 256 + threadIdx.x;
  if (t >= TT) return;
  float l[EE];
#pragma unroll
  for (int e = 0; e < EE; e++) l[e] = glog[t * EE + e];
  int i0 = 0; float v0 = l[0];
#pragma unroll
  for (int e = 1; e < EE; e++) if (l[e] > v0) { v0 = l[e]; i0 = e; }
  int i1 = -1; float v1 = -1e30f;
#pragma unroll
  for (int e = 0; e < EE; e++) if (e != i0 && l[e] > v1) { v1 = l[e]; i1 = e; }
  float e1 = __expf(v1 - v0);
  float inv = 1.f / (1.f + e1);
  tw[t * 2] = inv; tw[t * 2 + 1] = e1 * inv;
  tidx[t * 2] = i0; tidx[t * 2 + 1] = i1;
  atomicAdd(&counts[i0], 1);
  atomicAdd(&counts[i1], 1);
}

__global__ void k_scan(const int* __restrict__ counts, int* __restrict__ bases,
                       int* __restrict__ cursor) {
  int b = 0;
  for (int e = 0; e < EE; e++) { bases[e] = b; cursor[e] = b; b += counts[e]; }
}

__global__ void k_assign(const int* __restrict__ tidx, int* __restrict__ cursor,
                         int* __restrict__ rows, int* __restrict__ gtok) {
  int t = blockIdx.x * 256 + threadIdx.x;
  if (t >= TT) return;
#pragma unroll
  for (int kk = 0; kk < 2; kk++) {
    int e = tidx[t * 2 + kk];
    int r = atomicAdd(&cursor[e], 1);
    rows[t * 2 + kk] = r;
    gtok[r] = t;
  }
}

// ===== bf16 MFMA GEMM, m97-style global_load_lds staging (linear LDS) =====
// EPI: 0 = store f32 (+bias), 2 = gelu -> bf16 (+bias).
template<bool EXPERT, bool GATHER, bool BIAS, int EPI>
__global__ __launch_bounds__(256) void k_mfma2(
    const unsigned short* __restrict__ A, const unsigned short* __restrict__ Bt,
    const float* __restrict__ bias, void* __restrict__ Cv,
    int M, int N, int K,
    const int* __restrict__ gtok, const int* __restrict__ counts,
    const int* __restrict__ bases) {
  int cnt = M, base = 0;
  if (EXPERT) {
    int e = blockIdx.z;
    cnt = counts[e]; base = bases[e];
    if (BIAS) bias += (size_t)e * N;
    Bt += (size_t)e * N * K;
  }
  int m0 = blockIdx.y * 128;
  if (EXPERT && m0 >= cnt) return;
  int n0 = blockIdx.x * 128;

  __shared__ unsigned short As[128 * 32];   // linear [row][32k], 64B rows
  __shared__ unsigned short Bs[128 * 32];

  int tid = threadIdx.x, lane = tid & 63, w = tid >> 6;
  int r0 = w * 16 + (lane >> 2);            // staging row, issue 0 (0..63)
  int r1 = 64 + r0;                          // issue 1 (64..127)
  int kc = (lane & 3) * 8;                   // k-offset (elements)

  const unsigned short *pA0, *pA1;
  if (GATHER) {
    int t0 = (m0 + r0 < cnt) ? gtok[base + m0 + r0] : 0;
    int t1 = (m0 + r1 < cnt) ? gtok[base + m0 + r1] : 0;
    pA0 = A + (size_t)t0 * K + kc;
    pA1 = A + (size_t)t1 * K + kc;
  } else if (EXPERT) {
    int q0_ = (m0 + r0 < cnt) ? base + m0 + r0 : base;
    int q1_ = (m0 + r1 < cnt) ? base + m0 + r1 : base;
    pA0 = A + (size_t)q0_ * K + kc;
    pA1 = A + (size_t)q1_ * K + kc;
  } else {
    pA0 = A + (size_t)(m0 + r0) * K + kc;
    pA1 = A + (size_t)(m0 + r1) * K + kc;
  }
  const unsigned short* pB0 = Bt + (size_t)(n0 + r0) * K + kc;
  const unsigned short* pB1 = Bt + (size_t)(n0 + r1) * K + kc;

  unsigned short* dA0 = As + w * 512;        // wave-uniform LDS bases
  unsigned short* dA1 = As + 2048 + w * 512;
  unsigned short* dB0 = Bs + w * 512;
  unsigned short* dB1 = Bs + 2048 + w * 512;

  int wr = w >> 1, wc = w & 1;
  int l15 = lane & 15, lg = lane >> 4;
  const unsigned short* Ar = As + ((wr * 64 + l15) * 32 + lg * 8);
  const unsigned short* Br = Bs + ((wc * 64 + l15) * 32 + lg * 8);

  f32x4 acc[4][4];
#pragma unroll
  for (int i = 0; i < 4; i++)
#pragma unroll
    for (int j = 0; j < 4; j++) acc[i][j] = (f32x4){0.f, 0.f, 0.f, 0.f};

  for (int k0 = 0; k0 < K; k0 += 32) {
    GL16(dA0, pA0 + k0);
    GL16(dA1, pA1 + k0);
    GL16(dB0, pB0 + k0);
    GL16(dB1, pB1 + k0);
    __syncthreads();
    bf16x8 af[4], bfr[4];
#pragma unroll
    for (int f = 0; f < 4; f++) {
      af[f]  = *(const bf16x8*)(Ar + f * 512);
      bfr[f] = *(const bf16x8*)(Br + f * 512);
    }
#pragma unroll
    for (int i = 0; i < 4; i++)
#pragma unroll
      for (int j = 0; j < 4; j++)
        acc[i][j] = __builtin_amdgcn_mfma_f32_16x16x32_bf16(af[i], bfr[j], acc[i][j], 0, 0, 0);
    __syncthreads();
  }

#pragma unroll
  for (int j = 0; j < 4; j++) {
    int n = n0 + wc * 64 + j * 16 + l15;
    float bb = BIAS ? bias[n] : 0.f;
#pragma unroll
    for (int i = 0; i < 4; i++) {
      int mb = m0 + wr * 64 + i * 16 + lg * 4;
#pragma unroll
      for (int r = 0; r < 4; r++) {
        int m = mb + r;
        if (EXPERT && m >= cnt) continue;
        size_t off = (size_t)(base + m) * N + n;
        float v = acc[i][j][r] + bb;
        if (EPI == 0) {
          ((float*)Cv)[off] = v;
        } else {
          float g = 0.5f * v * (1.f + erff(v * 0.70710678118654752f));
          ((unsigned short*)Cv)[off] = f2b(g);
        }
      }
    }
  }
}

// ===== bf16 MFMA GEMM, register-staged, B from f32 (lm_head fallback) =====
__global__ __launch_bounds__(256) void k_mfma_bf32(
    const unsigned short* __restrict__ A, const float* __restrict__ Bf,
    float* __restrict__ C, int M, int N, int K) {
  int m0 = blockIdx.y * 128;
  int n0 = blockIdx.x * 128;
  __shared__ unsigned short As[128 * 40];
  __shared__ unsigned short Bs[128 * 40];
  int tid = threadIdx.x;
  int srow = tid >> 1;
  int scol = (tid & 1) * 16;
  const unsigned short* arow = A + (size_t)(m0 + srow) * K + scol;
  const float* browf = Bf + (size_t)(n0 + srow) * K + scol;
  unsigned short* As_w = As + srow * 40 + scol;
  unsigned short* Bs_w = Bs + srow * 40 + scol;
  int lane = tid & 63, wid = tid >> 6;
  int wr = wid >> 1, wc = wid & 1;
  int l15 = lane & 15, lg = lane >> 4;
  const unsigned short* Ar = As + ((wr * 64 + l15) * 40 + lg * 8);
  const unsigned short* Br = Bs + ((wc * 64 + l15) * 40 + lg * 8);
  f32x4 acc[4][4];
#pragma unroll
  for (int i = 0; i < 4; i++)
#pragma unroll
    for (int j = 0; j < 4; j++) acc[i][j] = (f32x4){0.f, 0.f, 0.f, 0.f};
  for (int k0 = 0; k0 < K; k0 += 32) {
    uint4 av0 = *(const uint4*)(arow + k0);
    uint4 av1 = *(const uint4*)(arow + k0 + 8);
    float4 f0 = *(const float4*)(browf + k0);
    float4 f1 = *(const float4*)(browf + k0 + 4);
    float4 f2 = *(const float4*)(browf + k0 + 8);
    float4 f3 = *(const float4*)(browf + k0 + 12);
    uint4 bv0 = make_uint4(pk2(f0.x, f0.y), pk2(f0.z, f0.w), pk2(f1.x, f1.y), pk2(f1.z, f1.w));
    uint4 bv1 = make_uint4(pk2(f2.x, f2.y), pk2(f2.z, f2.w), pk2(f3.x, f3.y), pk2(f3.z, f3.w));
    *(uint4*)As_w = av0; *(uint4*)(As_w + 8) = av1;
    *(uint4*)Bs_w = bv0; *(uint4*)(Bs_w + 8) = bv1;
    __syncthreads();
    bf16x8 af[4], bfr[4];
#pragma unroll
    for (int f = 0; f < 4; f++) {
      af[f]  = *(const bf16x8*)(Ar + f * 640);
      bfr[f] = *(const bf16x8*)(Br + f * 640);
    }
#pragma unroll
    for (int i = 0; i < 4; i++)
#pragma unroll
      for (int j = 0; j < 4; j++)
        acc[i][j] = __builtin_amdgcn_mfma_f32_16x16x32_bf16(af[i], bfr[j], acc[i][j], 0, 0, 0);
    __syncthreads();
  }
#pragma unroll
  for (int j = 0; j < 4; j++) {
    int n = n0 + wc * 64 + j * 16 + l15;
#pragma unroll
    for (int i = 0; i < 4; i++) {
      int mb = m0 + wr * 64 + i * 16 + lg * 4;
#pragma unroll
      for (int r = 0; r < 4; r++)
        C[(size_t)(mb + r) * N + n] = acc[i][j][r];
    }
  }
}

// ---------------- MoE scatter (bf16 path): x += w0*go[r0] + w1*go[r1] ----------------
__global__ __launch_bounds__(256) void k_scatter(const float* __restrict__ go,
    const int* __restrict__ rows, const float* __restrict__ tw, float* __restrict__ x) {
  int t = blockIdx.x;
  int r0 = rows[t * 2], r1 = rows[t * 2 + 1];
  float w0 = tw[t * 2], w1 = tw[t * 2 + 1];
  float* xr = x + (size_t)t * DD;
  const float* g0 = go + (size_t)r0 * DD;
  const float* g1 = go + (size_t)r1 * DD;
  for (int d = threadIdx.x; d < DD; d += 256)
    xr[d] += w0 * g0[d] + w1 * g1[d];
}

// ================= host =================
extern "C" void kernel_launch(void* const* d_in, const int* in_sizes, int n_in,
                              void* d_out, int out_size, void* d_ws, size_t ws_size,
                              hipStream_t stream) {
  (void)in_sizes; (void)n_in; (void)out_size;
  const int* tok   = (const int*)d_in[0];
  const float* emb = (const float*)d_in[1];
  const float* pos = (const float*)d_in[2];
  const float* wq  = (const float*)d_in[3];
  const float* bq  = (const float*)d_in[4];
  const float* wk  = (const float*)d_in[5];
  const float* bk  = (const float*)d_in[6];
  const float* wv  = (const float*)d_in[7];
  const float* bvv = (const float*)d_in[8];
  const float* wo  = (const float*)d_in[9];
  const float* bo  = (const float*)d_in[10];
  const float* ln1 = (const float*)d_in[11];
  const float* ln2 = (const float*)d_in[12];
  const float* gw  = (const float*)d_in[13];
  const float* gb  = (const float*)d_in[14];
  const float* w1  = (const float*)d_in[15];
  const float* b1  = (const float*)d_in[16];
  const float* w2  = (const float*)d_in[17];
  const float* b2  = (const float*)d_in[18];
  const float* lnf = (const float*)d_in[19];

  // ---- scratch carved from d_out (65.5M f32; all dead before lm_head) ----
  float* fp = (float*)d_out;
  float* qb   = fp; fp += (size_t)TT * DD;
  float* kb   = fp; fp += (size_t)TT * DD;
  float* vb   = fp; fp += (size_t)TT * DD;
  float* ao   = fp; fp += (size_t)TT * DD;
  float* x    = fp; fp += (size_t)TT * DD;
  float* h    = fp; fp += (size_t)TT * DD;
  float* gh1  = fp; fp += (size_t)TT * 2 * FF;      // f32, layer-1 experts
  float* go   = fp; fp += (size_t)TT * 2 * DD;
  float* glog = fp; fp += (size_t)TT * EE;
  float* tw   = fp; fp += (size_t)TT * 2;
  int* tidx   = (int*)fp; fp += TT * 2;
  int* rows   = (int*)fp; fp += TT * 2;
  int* gtok   = (int*)fp; fp += TT * 2;
  int* counts = (int*)fp; fp += 16;
  int* cursor = (int*)fp; fp += 16;
  int* bases  = (int*)fp; fp += 16;
  unsigned short* hb   = (unsigned short*)fp; fp += (size_t)TT * DD / 2;
  unsigned short* gh1b = (unsigned short*)fp; fp += (size_t)TT * 2 * FF / 2;
  unsigned short* w1t  = (unsigned short*)fp; fp += (size_t)EE * DD * FF / 2;  // layer-2 only
  unsigned short* w2t  = (unsigned short*)fp; fp += (size_t)EE * FF * DD / 2;
  float* part = fp; fp += (size_t)4 * 4096 * DD;    // split-K partials, 12.58M
  // total ~63.8M floats < 65.5M

  // d_ws: hf (bf16 final activations, must survive lm_head) + optional embT
  unsigned short* hf = (unsigned short*)d_ws;
  unsigned short* embT = (unsigned short*)d_ws + (size_t)TT * DD;
  bool useEmbT = ws_size >= (size_t)TT * DD * 2 + (size_t)VV * DD * 2;

  // ---- pre-pass ----
  k_embed<<<TT, 256, 0, stream>>>(tok, emb, pos, x);
  k_tcvt<<<dim3(96, 24, EE), 256, 0, stream>>>(w1 + (size_t)1 * EE * DD * FF, w1t,
      DD, FF, (size_t)DD * FF, (size_t)DD * FF);
  k_tcvt<<<dim3(24, 96, EE), 256, 0, stream>>>(w2 + (size_t)1 * EE * FF * DD, w2t,
      FF, DD, (size_t)FF * DD, (size_t)FF * DD);
  if (useEmbT)
    k_cvt<<<(VV * DD) / (256 * 8), 256, 0, stream>>>(emb, embT);

  for (int l = 0; l < NLAYER; l++) {
    const float* wq_l = wq + (size_t)l * DD * DD;
    const float* wk_l = wk + (size_t)l * DD * DD;
    const float* wv_l = wv + (size_t)l * DD * DD;
    const float* wo_l = wo + (size_t)l * DD * DD;

    // attention block (f32 — feeds routers)
    k_rmsnorm<<<TT, 256, 0, stream>>>(x, ln1 + (size_t)l * DD, h, hb);
    // QKV: split-K=2, 3 column-thirds
    k_skf32<<<dim3(18, 16, 2), 256, 0, stream>>>(h, wq_l, wk_l, wv_l,
        part, TT, 2304, 768, 768, 384, 2, TT);
    k_qkvred<<<TT, 256, 0, stream>>>(part, bq + (size_t)l * DD, bk + (size_t)l * DD,
        bvv + (size_t)l * DD, qb, kb, vb);
    k_attn<<<dim3(SS / QBLK, HH, BB), 256, 0, stream>>>(qb, kb, vb, ao);
    // O-proj: split-K=4
    k_skf32<<<dim3(6, 16, 4), 256, 0, stream>>>(ao, wo_l, wo_l, wo_l,
        part, TT, 768, 768, 768, 192, 4, TT);
    k_ored<<<TT, 256, 0, stream>>>(part, bo + (size_t)l * DD, x);

    // MoE block
    k_rmsnorm<<<TT, 256, 0, stream>>>(x, ln2 + (size_t)l * DD, h, hb);
    k_gate<<<TT, 256, 0, stream>>>(h, gw + (size_t)l * DD * EE, gb + (size_t)l * EE, glog);
    k_zero<<<1, 64, 0, stream>>>(counts, cursor);
    k_router<<<TT / 256, 256, 0, stream>>>(glog, tidx, tw, counts);
    k_scan<<<1, 1, 0, stream>>>(counts, bases, cursor);
    k_assign<<<TT / 256, 256, 0, stream>>>(tidx, cursor, rows, gtok);
    if (l < NLAYER - 1) {
      // feeds next layer's router -> f32 experts (wide microtile)
      k_e1w<<<dim3(FF / 256, 32, EE), 128, 0, stream>>>(
          h, w1 + (size_t)l * EE * DD * FF, b1 + (size_t)l * EE * FF,
          gtok, counts, bases, gh1);
      k_e2w<<<dim3(3, 32, 32), 128, 0, stream>>>(
          gh1, w2 + (size_t)l * EE * FF * DD, counts, bases, part);
      k_e2red<<<TT, 256, 0, stream>>>(part, rows, tidx, tw,
          b2 + (size_t)l * EE * DD, x);
    } else {
      // last layer: routing-irrelevant -> bf16 MFMA (gload_lds staging)
      k_mfma2<true, true, true, 2><<<dim3(FF / 128, TT / 128, EE), 256, 0, stream>>>(
          hb, w1t, b1 + (size_t)l * EE * FF, gh1b,
          TT, FF, DD, gtok, counts, bases);
      k_mfma2<true, false, true, 0><<<dim3(DD / 128, TT / 128, EE), 256, 0, stream>>>(
          gh1b, w2t, b2 + (size_t)l * EE * DD, go,
          TT, DD, FF, gtok, counts, bases);
      k_scatter<<<TT, 256, 0, stream>>>(go, rows, tw, x);
    }
  }

  // final norm + lm_head (bf16 MFMA)
  k_rmsnorm<<<TT, 256, 0, stream>>>(x, lnf, h, hf);
  if (useEmbT) {
    k_mfma2<false, false, false, 0><<<dim3(VV / 128, TT / 128), 256, 0, stream>>>(
        hf, embT, nullptr, (float*)d_out,
        TT, VV, DD, nullptr, nullptr, nullptr);
  } else {
    k_mfma_bf32<<<dim3(VV / 128, TT / 128), 256, 0, stream>>>(
        hf, emb, (float*)d_out, TT, VV, DD);
  }
}

// Round 10
// 2274.924 us; speedup vs baseline: 1.6495x; 1.6495x over previous
//
#include <hip/hip_runtime.h>
#include <math.h>

#define TT 2048      // B*S tokens
#define BB 2
#define SS 1024
#define DD 768
#define HH 12
#define FF 3072
#define EE 8
#define VV 32000
#define NLAYER 2
#define QBLK 8

typedef __attribute__((ext_vector_type(8))) short bf16x8;
typedef __attribute__((ext_vector_type(4))) float f32x4;

#define GL16(ldst, gsrc) __builtin_amdgcn_global_load_lds( \
    (const __attribute__((address_space(1))) void*)(gsrc), \
    (__attribute__((address_space(3))) void*)(ldst), 16, 0, 0)

static __device__ __forceinline__ unsigned short f2b(float f) {
  unsigned u = __float_as_uint(f);
  unsigned r = (u + 0x7fffu + ((u >> 16) & 1u)) >> 16;
  return (unsigned short)r;
}
static __device__ __forceinline__ unsigned int pk2(float a, float b) {
  return (unsigned int)f2b(a) | ((unsigned int)f2b(b) << 16);
}

// ---------------- embedding: x = emb[tok] + pos ----------------
__global__ __launch_bounds__(256) void k_embed(const int* __restrict__ tok,
    const float* __restrict__ emb, const float* __restrict__ pos,
    float* __restrict__ x) {
  int t = blockIdx.x;
  int s = t & (SS - 1);
  int tk = tok[t];
  const float* er = emb + (size_t)tk * DD;
  const float* pr = pos + (size_t)s * DD;
  float* xr = x + (size_t)t * DD;
  for (int d = threadIdx.x; d < DD; d += 256)
    xr[d] = er[d] + pr[d];
}

// ------------- rmsnorm: writes f32 out AND bf16 out -------------
__global__ __launch_bounds__(256) void k_rmsnorm(const float* __restrict__ x,
    const float* __restrict__ w, float* __restrict__ out,
    unsigned short* __restrict__ outb) {
  int t = blockIdx.x;
  const float* xr = x + (size_t)t * DD;
  int tid = threadIdx.x;
  float v0 = xr[tid], v1 = xr[tid + 256], v2 = xr[tid + 512];
  float ss = v0 * v0 + v1 * v1 + v2 * v2;
  for (int off = 32; off > 0; off >>= 1) ss += __shfl_down(ss, off, 64);
  __shared__ float ps[4];
  int wid = tid >> 6, lane = tid & 63;
  if (lane == 0) ps[wid] = ss;
  __syncthreads();
  float r = rsqrtf((ps[0] + ps[1] + ps[2] + ps[3]) * (1.0f / DD) + 1e-6f);
  float* orow = out + (size_t)t * DD;
  unsigned short* brow = outb + (size_t)t * DD;
  float o0 = v0 * r * w[tid], o1 = v1 * r * w[tid + 256], o2 = v2 * r * w[tid + 512];
  orow[tid] = o0; orow[tid + 256] = o1; orow[tid + 512] = o2;
  brow[tid] = f2b(o0); brow[tid + 256] = f2b(o1); brow[tid + 512] = f2b(o2);
}

// ------------- transpose+convert: f32 [R][C] -> bf16 [C][R] -------------
__global__ __launch_bounds__(256) void k_tcvt(const float* __restrict__ src,
    unsigned short* __restrict__ dst, int R, int C, size_t srcZ, size_t dstZ) {
  src += (size_t)blockIdx.z * srcZ;
  dst += (size_t)blockIdx.z * dstZ;
  __shared__ unsigned short tile[32][40];
  int t = threadIdx.x;
  int r = t >> 3, c4 = (t & 7) * 4;
  int r0 = blockIdx.y * 32, c0 = blockIdx.x * 32;
  float4 v = *(const float4*)(src + (size_t)(r0 + r) * C + c0 + c4);
  tile[r][c4 + 0] = f2b(v.x); tile[r][c4 + 1] = f2b(v.y);
  tile[r][c4 + 2] = f2b(v.z); tile[r][c4 + 3] = f2b(v.w);
  __syncthreads();
  int cc = t >> 3, r4 = (t & 7) * 4;
  ushort4 o;
  o.x = tile[r4 + 0][cc]; o.y = tile[r4 + 1][cc];
  o.z = tile[r4 + 2][cc]; o.w = tile[r4 + 3][cc];
  *(ushort4*)(dst + (size_t)(c0 + cc) * R + r0 + r4) = o;
}

// ------------- straight convert f32 -> bf16 (same layout) -------------
__global__ __launch_bounds__(256) void k_cvt(const float* __restrict__ src,
    unsigned short* __restrict__ dst) {
  size_t i = ((size_t)blockIdx.x * 256 + threadIdx.x) * 8;
  float4 a = *(const float4*)(src + i);
  float4 b = *(const float4*)(src + i + 4);
  ushort4 o0, o1;
  o0.x = f2b(a.x); o0.y = f2b(a.y); o0.z = f2b(a.z); o0.w = f2b(a.w);
  o1.x = f2b(b.x); o1.y = f2b(b.y); o1.z = f2b(b.z); o1.w = f2b(b.w);
  *(ushort4*)(dst + i) = o0;
  *(ushort4*)(dst + i + 4) = o1;
}

// ======== f32 split-K 128x128 GEMM, software-pipelined staging (R8-proven) ========
template<bool EXPERT>
__global__ __launch_bounds__(256) void k_skf32(
    const float* __restrict__ A, const float* __restrict__ W0,
    const float* __restrict__ W1, const float* __restrict__ W2,
    float* __restrict__ part, int M, int Ntot, int Nthird, int K, int KC,
    int nsplit, int prows,
    const int* __restrict__ counts, const int* __restrict__ bases) {
  int s, base = 0, cnt = M, sel = 0, n0;
  const float* W;
  if (EXPERT) {
    int z = blockIdx.z;
    s = z % nsplit;
    int e = z / nsplit;
    cnt = counts[e]; base = bases[e];
    W = W0 + (size_t)e * K * Nthird;
    n0 = blockIdx.x * 128;
  } else {
    s = blockIdx.z;
    int tpn = Nthird >> 7;
    sel = blockIdx.x / tpn;
    n0 = (blockIdx.x - sel * tpn) * 128;
    W = sel == 0 ? W0 : sel == 1 ? W1 : W2;
  }
  int m0 = blockIdx.y * 128;
  if (EXPERT && m0 >= cnt) return;
  int kbase = s * KC;

  __shared__ float As[16][132];   // k-major: As[k][m]
  __shared__ float Bs[16][132];
  int tid = threadIdx.x;
  int tx = tid & 15, ty = tid >> 4;
  int ra = tid >> 1, ka0 = (tid & 1) * 8;
  int kb = tid >> 4, nb0 = (tid & 15) * 8;
  bool arow_ok = !EXPERT || (m0 + ra < cnt);
  const float* Arow = A + (size_t)(EXPERT ? (base + m0 + (arow_ok ? ra : 0))
                                          : (m0 + ra)) * K + kbase;
  float acc[8][8] = {};

  // prologue: tile 0 -> regs
  float4 av0 = make_float4(0.f, 0.f, 0.f, 0.f), av1 = av0, bv0, bv1;
  if (arow_ok) {
    av0 = *(const float4*)(Arow + ka0);
    av1 = *(const float4*)(Arow + ka0 + 4);
  }
  {
    const float* Wrow = W + (size_t)(kbase + kb) * Nthird + n0 + nb0;
    bv0 = *(const float4*)(Wrow);
    bv1 = *(const float4*)(Wrow + 4);
  }

  for (int k0 = 0; k0 < KC; k0 += 16) {
    As[ka0 + 0][ra] = av0.x; As[ka0 + 1][ra] = av0.y;
    As[ka0 + 2][ra] = av0.z; As[ka0 + 3][ra] = av0.w;
    As[ka0 + 4][ra] = av1.x; As[ka0 + 5][ra] = av1.y;
    As[ka0 + 6][ra] = av1.z; As[ka0 + 7][ra] = av1.w;
    *(float4*)&Bs[kb][nb0] = bv0;
    *(float4*)&Bs[kb][nb0 + 4] = bv1;
    __syncthreads();
    float4 nav0 = make_float4(0.f, 0.f, 0.f, 0.f), nav1 = nav0, nbv0 = nav0, nbv1 = nav0;
    if (k0 + 16 < KC) {
      if (arow_ok) {
        nav0 = *(const float4*)(Arow + k0 + 16 + ka0);
        nav1 = *(const float4*)(Arow + k0 + 16 + ka0 + 4);
      }
      const float* Wn = W + (size_t)(kbase + k0 + 16 + kb) * Nthird + n0 + nb0;
      nbv0 = *(const float4*)(Wn);
      nbv1 = *(const float4*)(Wn + 4);
    }
#pragma unroll
    for (int kk = 0; kk < 16; kk++) {
      float4 a0 = *(const float4*)&As[kk][ty * 8];
      float4 a1 = *(const float4*)&As[kk][ty * 8 + 4];
      float4 b0 = *(const float4*)&Bs[kk][tx * 8];
      float4 b1 = *(const float4*)&Bs[kk][tx * 8 + 4];
      float a[8] = {a0.x, a0.y, a0.z, a0.w, a1.x, a1.y, a1.z, a1.w};
      float b[8] = {b0.x, b0.y, b0.z, b0.w, b1.x, b1.y, b1.z, b1.w};
#pragma unroll
      for (int i = 0; i < 8; i++) {
#pragma unroll
        for (int j = 0; j < 8; j++) acc[i][j] = fmaf(a[i], b[j], acc[i][j]);
      }
    }
    __syncthreads();
    av0 = nav0; av1 = nav1; bv0 = nbv0; bv1 = nbv1;
  }
#pragma unroll
  for (int i = 0; i < 8; i++) {
    int m = m0 + ty * 8 + i;
    if (EXPERT && m >= cnt) continue;
    size_t prow = EXPERT ? ((size_t)s * prows + base + m) : ((size_t)s * M + m);
    float* orow = part + prow * Ntot + sel * Nthird;
#pragma unroll
    for (int j = 0; j < 8; j++)
      orow[n0 + tx * 8 + j] = acc[i][j];
  }
}

// ---- QKV reduce: q/k/v = part0+part1 + bias ----
__global__ __launch_bounds__(256) void k_qkvred(const float* __restrict__ part,
    const float* __restrict__ bq, const float* __restrict__ bk,
    const float* __restrict__ bv, float* __restrict__ qb,
    float* __restrict__ kb, float* __restrict__ vb) {
  int t = blockIdx.x;
  for (int c = threadIdx.x; c < 2304; c += 256) {
    float v = part[(size_t)t * 2304 + c] + part[((size_t)TT + t) * 2304 + c];
    if (c < 768)       qb[(size_t)t * DD + c] = v + bq[c];
    else if (c < 1536) kb[(size_t)t * DD + c - 768] = v + bk[c - 768];
    else               vb[(size_t)t * DD + c - 1536] = v + bv[c - 1536];
  }
}

// ---- O-proj reduce: x += sum(part[0..3]) + bo ----
__global__ __launch_bounds__(256) void k_ored(const float* __restrict__ part,
    const float* __restrict__ bo, float* __restrict__ x) {
  int t = blockIdx.x;
  for (int d = threadIdx.x; d < DD; d += 256) {
    float v = part[(size_t)t * DD + d]
            + part[((size_t)TT + t) * DD + d]
            + part[((size_t)2 * TT + t) * DD + d]
            + part[((size_t)3 * TT + t) * DD + d];
    x[(size_t)t * DD + d] += v + bo[d];
  }
}

// ---- expert2 reduce + gate-weighted scatter: x += w*(sum(part)+b2) ----
__global__ __launch_bounds__(256) void k_e2red(const float* __restrict__ part,
    const int* __restrict__ rows, const int* __restrict__ tidx,
    const float* __restrict__ tw, const float* __restrict__ b2,
    float* __restrict__ x) {
  int t = blockIdx.x;
  int r0 = rows[t * 2], r1 = rows[t * 2 + 1];
  int e0 = tidx[t * 2], e1 = tidx[t * 2 + 1];
  float w0 = tw[t * 2], w1 = tw[t * 2 + 1];
  for (int d = threadIdx.x; d < DD; d += 256) {
    float v0 = part[(size_t)r0 * DD + d]
             + part[((size_t)4096 + r0) * DD + d]
             + part[((size_t)8192 + r0) * DD + d]
             + part[((size_t)12288 + r0) * DD + d] + b2[e0 * DD + d];
    float v1 = part[(size_t)r1 * DD + d]
             + part[((size_t)4096 + r1) * DD + d]
             + part[((size_t)8192 + r1) * DD + d]
             + part[((size_t)12288 + r1) * DD + d] + b2[e1 * DD + d];
    x[(size_t)t * DD + d] += w0 * v0 + w1 * v1;
  }
}

// ---------------- attention (f32, separate q/k/v) ----------------
__global__ __launch_bounds__(256) void k_attn(const float* __restrict__ q,
    const float* __restrict__ k, const float* __restrict__ v, float* __restrict__ ao) {
  int b = blockIdx.z, hh = blockIdx.y, q0 = blockIdx.x * QBLK;
  __shared__ float qs[QBLK][64];
  __shared__ float sc[QBLK][SS];
  __shared__ float red[QBLK][8];
  int tid = threadIdx.x;
  const size_t hoff = (size_t)b * SS * DD + (size_t)hh * 64;
  for (int i = tid; i < QBLK * 64; i += 256) {
    int qi = i >> 6, d = i & 63;
    qs[qi][d] = q[hoff + (size_t)(q0 + qi) * DD + d];
  }
  __syncthreads();
  int kmax = q0 + QBLK;
  for (int j = tid; j < kmax; j += 256) {
    const float* kr = k + hoff + (size_t)j * DD;
    float p[QBLK];
#pragma unroll
    for (int qi = 0; qi < QBLK; qi++) p[qi] = 0.f;
#pragma unroll 4
    for (int c = 0; c < 16; c++) {
      float4 kv = *(const float4*)(kr + c * 4);
#pragma unroll
      for (int qi = 0; qi < QBLK; qi++)
        p[qi] += qs[qi][c * 4] * kv.x + qs[qi][c * 4 + 1] * kv.y +
                 qs[qi][c * 4 + 2] * kv.z + qs[qi][c * 4 + 3] * kv.w;
    }
#pragma unroll
    for (int qi = 0; qi < QBLK; qi++)
      sc[qi][j] = (j <= q0 + qi) ? p[qi] * 0.125f : -1e30f;
  }
  __syncthreads();
  int wid = tid >> 6, lane = tid & 63;
#pragma unroll
  for (int qi = 0; qi < QBLK; qi++) {
    float mx = -1e30f;
    for (int j = tid; j < kmax; j += 256) mx = fmaxf(mx, sc[qi][j]);
    for (int off = 32; off > 0; off >>= 1) mx = fmaxf(mx, __shfl_down(mx, off, 64));
    if (lane == 0) red[qi][wid] = mx;
  }
  __syncthreads();
#pragma unroll
  for (int qi = 0; qi < QBLK; qi++) {
    float mx = fmaxf(fmaxf(red[qi][0], red[qi][1]), fmaxf(red[qi][2], red[qi][3]));
    float s = 0.f;
    for (int j = tid; j < kmax; j += 256) {
      float e = __expf(sc[qi][j] - mx);
      sc[qi][j] = e;
      s += e;
    }
    for (int off = 32; off > 0; off >>= 1) s += __shfl_down(s, off, 64);
    if (lane == 0) red[qi][4 + wid] = s;
  }
  __syncthreads();
  int d = tid & 63, g = tid >> 6;
  for (int qi = g; qi < QBLK; qi += 4) {
    float inv = 1.f / (red[qi][4] + red[qi][5] + red[qi][6] + red[qi][7]);
    int jend = q0 + qi + 1;
    const float* vp = v + hoff + d;
    float a0 = 0.f, a1 = 0.f, a2 = 0.f, a3 = 0.f;
    int j = 0;
    for (; j + 4 <= jend; j += 4) {
      a0 = fmaf(sc[qi][j],     vp[(size_t)j * DD], a0);
      a1 = fmaf(sc[qi][j + 1], vp[(size_t)(j + 1) * DD], a1);
      a2 = fmaf(sc[qi][j + 2], vp[(size_t)(j + 2) * DD], a2);
      a3 = fmaf(sc[qi][j + 3], vp[(size_t)(j + 3) * DD], a3);
    }
    for (; j < jend; j++) a0 = fmaf(sc[qi][j], vp[(size_t)j * DD], a0);
    float acc = (a0 + a2) + (a1 + a3);
    ao[hoff + (size_t)(q0 + qi) * DD + d] = acc * inv;
  }
}

// ---------------- gate logits ----------------
__global__ __launch_bounds__(256) void k_gate(const float* __restrict__ h,
    const float* __restrict__ gw, const float* __restrict__ gb,
    float* __restrict__ glog) {
  __shared__ float hr[DD];
  int t = blockIdx.x;
  for (int d = threadIdx.x; d < DD; d += 256) hr[d] = h[(size_t)t * DD + d];
  __syncthreads();
  int e = threadIdx.x >> 5, j = threadIdx.x & 31;
  float s = 0.f;
  for (int d = j; d < DD; d += 32) s += hr[d] * gw[d * EE + e];
  for (int off = 16; off > 0; off >>= 1) s += __shfl_down(s, off, 32);
  if (j == 0) glog[t * EE + e] = s + gb[e];
}

// ---------------- router ----------------
__global__ void k_zero(int* counts, int* cursor) {
  int i = threadIdx.x;
  if (i < EE) { counts[i] = 0; cursor[i] = 0; }
}

__global__ void k_router(const float* __restrict__ glog, int* __restrict__ tidx,
    float* __restrict__ tw, int* __restrict__ counts) {
  int t = blockIdx.x * 256 + threadIdx.x;
  if (t >= TT) return;
  float l[EE];
#pragma unroll
  for (int e = 0; e < EE; e++) l[e] = glog[t * EE + e];
  int i0 = 0; float v0 = l[0];
#pragma unroll
  for (int e = 1; e < EE; e++) if (l[e] > v0) { v0 = l[e]; i0 = e; }
  int i1 = -1; float v1 = -1e30f;
#pragma unroll
  for (int e = 0; e < EE; e++) if (e != i0 && l[e] > v1) { v1 = l[e]; i1 = e; }
  float e1 = __expf(v1 - v0);
  float inv = 1.f / (1.f + e1);
  tw[t * 2] = inv; tw[t * 2 + 1] = e1 * inv;
  tidx[t * 2] = i0; tidx[t * 2 + 1] = i1;
  atomicAdd(&counts[i0], 1);
  atomicAdd(&counts[i1], 1);
}

__global__ void k_scan(const int* __restrict__ counts, int* __restrict__ bases,
                       int* __restrict__ cursor) {
  int b = 0;
  for (int e = 0; e < EE; e++) { bases[e] = b; cursor[e] = b; b += counts[e]; }
}

__global__ void k_assign(const int* __restrict__ tidx, int* __restrict__ cursor,
                         int* __restrict__ rows, int* __restrict__ gtok) {
  int t = blockIdx.x * 256 + threadIdx.x;
  if (t >= TT) return;
#pragma unroll
  for (int kk = 0; kk < 2; kk++) {
    int e = tidx[t * 2 + kk];
    int r = atomicAdd(&cursor[e], 1);
    rows[t * 2 + kk] = r;
    gtok[r] = t;
  }
}

// ------- f32 expert FFN1, pipelined staging (R8-proven, feeds router) -------
__global__ __launch_bounds__(256) void k_expert1(const float* __restrict__ h,
    const float* __restrict__ w1, const float* __restrict__ b1,
    const int* __restrict__ gtok, const int* __restrict__ counts,
    const int* __restrict__ bases, float* __restrict__ gh1) {
  int e = blockIdx.z;
  int cnt = counts[e];
  int m0 = blockIdx.y * 128;
  if (m0 >= cnt) return;
  int base = bases[e];
  int n0 = blockIdx.x * 128;
  const float* W = w1 + (size_t)e * DD * FF;
  __shared__ float As[16][132];   // k-major
  __shared__ float Bs[16][132];
  int tid = threadIdx.x;
  int tx = tid & 15, ty = tid >> 4;
  int ra = tid >> 1, ka0 = (tid & 1) * 8;
  int kb = tid >> 4, nb0 = (tid & 15) * 8;
  int tok = (m0 + ra < cnt) ? gtok[base + m0 + ra] : -1;
  const float* Arow = h + (size_t)(tok < 0 ? 0 : tok) * DD;
  float acc[8][8] = {};

  float4 av0 = make_float4(0.f, 0.f, 0.f, 0.f), av1 = av0, bv0, bv1;
  if (tok >= 0) {
    av0 = *(const float4*)(Arow + ka0);
    av1 = *(const float4*)(Arow + ka0 + 4);
  }
  {
    const float* Wrow = W + (size_t)kb * FF + n0 + nb0;
    bv0 = *(const float4*)(Wrow);
    bv1 = *(const float4*)(Wrow + 4);
  }

  for (int k0 = 0; k0 < DD; k0 += 16) {
    As[ka0 + 0][ra] = av0.x; As[ka0 + 1][ra] = av0.y;
    As[ka0 + 2][ra] = av0.z; As[ka0 + 3][ra] = av0.w;
    As[ka0 + 4][ra] = av1.x; As[ka0 + 5][ra] = av1.y;
    As[ka0 + 6][ra] = av1.z; As[ka0 + 7][ra] = av1.w;
    *(float4*)&Bs[kb][nb0] = bv0;
    *(float4*)&Bs[kb][nb0 + 4] = bv1;
    __syncthreads();
    float4 nav0 = make_float4(0.f, 0.f, 0.f, 0.f), nav1 = nav0, nbv0 = nav0, nbv1 = nav0;
    if (k0 + 16 < DD) {
      if (tok >= 0) {
        nav0 = *(const float4*)(Arow + k0 + 16 + ka0);
        nav1 = *(const float4*)(Arow + k0 + 16 + ka0 + 4);
      }
      const float* Wn = W + (size_t)(k0 + 16 + kb) * FF + n0 + nb0;
      nbv0 = *(const float4*)(Wn);
      nbv1 = *(const float4*)(Wn + 4);
    }
#pragma unroll
    for (int kk = 0; kk < 16; kk++) {
      float4 a0 = *(const float4*)&As[kk][ty * 8];
      float4 a1 = *(const float4*)&As[kk][ty * 8 + 4];
      float4 b0 = *(const float4*)&Bs[kk][tx * 8];
      float4 b1 = *(const float4*)&Bs[kk][tx * 8 + 4];
      float a[8] = {a0.x, a0.y, a0.z, a0.w, a1.x, a1.y, a1.z, a1.w};
      float b[8] = {b0.x, b0.y, b0.z, b0.w, b1.x, b1.y, b1.z, b1.w};
#pragma unroll
      for (int i = 0; i < 8; i++) {
#pragma unroll
        for (int j = 0; j < 8; j++) acc[i][j] = fmaf(a[i], b[j], acc[i][j]);
      }
    }
    __syncthreads();
    av0 = nav0; av1 = nav1; bv0 = nbv0; bv1 = nbv1;
  }
#pragma unroll
  for (int i = 0; i < 8; i++) {
    int m = m0 + ty * 8 + i;
    if (m >= cnt) continue;
    float* orow = gh1 + (size_t)(base + m) * FF;
#pragma unroll
    for (int j = 0; j < 8; j++) {
      int n = n0 + tx * 8 + j;
      float vv = acc[i][j] + b1[e * FF + n];
      orow[n] = 0.5f * vv * (1.f + erff(vv * 0.70710678118654752f));
    }
  }
}

// ===== bf16 MFMA GEMM, m97-style global_load_lds staging (linear LDS) =====
// EPI: 0 = store f32 (+bias), 2 = gelu -> bf16 (+bias).
template<bool EXPERT, bool GATHER, bool BIAS, int EPI>
__global__ __launch_bounds__(256) void k_mfma2(
    const unsigned short* __restrict__ A, const unsigned short* __restrict__ Bt,
    const float* __restrict__ bias, void* __restrict__ Cv,
    int M, int N, int K,
    const int* __restrict__ gtok, const int* __restrict__ counts,
    const int* __restrict__ bases) {
  int cnt = M, base = 0;
  if (EXPERT) {
    int e = blockIdx.z;
    cnt = counts[e]; base = bases[e];
    if (BIAS) bias += (size_t)e * N;
    Bt += (size_t)e * N * K;
  }
  int m0 = blockIdx.y * 128;
  if (EXPERT && m0 >= cnt) return;
  int n0 = blockIdx.x * 128;

  __shared__ unsigned short As[128 * 32];   // linear [row][32k], 64B rows
  __shared__ unsigned short Bs[128 * 32];

  int tid = threadIdx.x, lane = tid & 63, w = tid >> 6;
  int r0 = w * 16 + (lane >> 2);            // staging row, issue 0 (0..63)
  int r1 = 64 + r0;                          // issue 1 (64..127)
  int kc = (lane & 3) * 8;                   // k-offset (elements)

  const unsigned short *pA0, *pA1;
  if (GATHER) {
    int t0 = (m0 + r0 < cnt) ? gtok[base + m0 + r0] : 0;
    int t1 = (m0 + r1 < cnt) ? gtok[base + m0 + r1] : 0;
    pA0 = A + (size_t)t0 * K + kc;
    pA1 = A + (size_t)t1 * K + kc;
  } else if (EXPERT) {
    int q0_ = (m0 + r0 < cnt) ? base + m0 + r0 : base;
    int q1_ = (m0 + r1 < cnt) ? base + m0 + r1 : base;
    pA0 = A + (size_t)q0_ * K + kc;
    pA1 = A + (size_t)q1_ * K + kc;
  } else {
    pA0 = A + (size_t)(m0 + r0) * K + kc;
    pA1 = A + (size_t)(m0 + r1) * K + kc;
  }
  const unsigned short* pB0 = Bt + (size_t)(n0 + r0) * K + kc;
  const unsigned short* pB1 = Bt + (size_t)(n0 + r1) * K + kc;

  unsigned short* dA0 = As + w * 512;        // wave-uniform LDS bases
  unsigned short* dA1 = As + 2048 + w * 512;
  unsigned short* dB0 = Bs + w * 512;
  unsigned short* dB1 = Bs + 2048 + w * 512;

  int wr = w >> 1, wc = w & 1;
  int l15 = lane & 15, lg = lane >> 4;
  const unsigned short* Ar = As + ((wr * 64 + l15) * 32 + lg * 8);
  const unsigned short* Br = Bs + ((wc * 64 + l15) * 32 + lg * 8);

  f32x4 acc[4][4];
#pragma unroll
  for (int i = 0; i < 4; i++)
#pragma unroll
    for (int j = 0; j < 4; j++) acc[i][j] = (f32x4){0.f, 0.f, 0.f, 0.f};

  for (int k0 = 0; k0 < K; k0 += 32) {
    GL16(dA0, pA0 + k0);
    GL16(dA1, pA1 + k0);
    GL16(dB0, pB0 + k0);
    GL16(dB1, pB1 + k0);
    __syncthreads();
    bf16x8 af[4], bfr[4];
#pragma unroll
    for (int f = 0; f < 4; f++) {
      af[f]  = *(const bf16x8*)(Ar + f * 512);
      bfr[f] = *(const bf16x8*)(Br + f * 512);
    }
#pragma unroll
    for (int i = 0; i < 4; i++)
#pragma unroll
      for (int j = 0; j < 4; j++)
        acc[i][j] = __builtin_amdgcn_mfma_f32_16x16x32_bf16(af[i], bfr[j], acc[i][j], 0, 0, 0);
    __syncthreads();
  }

#pragma unroll
  for (int j = 0; j < 4; j++) {
    int n = n0 + wc * 64 + j * 16 + l15;
    float bb = BIAS ? bias[n] : 0.f;
#pragma unroll
    for (int i = 0; i < 4; i++) {
      int mb = m0 + wr * 64 + i * 16 + lg * 4;
#pragma unroll
      for (int r = 0; r < 4; r++) {
        int m = mb + r;
        if (EXPERT && m >= cnt) continue;
        size_t off = (size_t)(base + m) * N + n;
        float v = acc[i][j][r] + bb;
        if (EPI == 0) {
          ((float*)Cv)[off] = v;
        } else {
          float g = 0.5f * v * (1.f + erff(v * 0.70710678118654752f));
          ((unsigned short*)Cv)[off] = f2b(g);
        }
      }
    }
  }
}

// ===== bf16 MFMA GEMM, register-staged, B from f32 (lm_head fallback) =====
__global__ __launch_bounds__(256) void k_mfma_bf32(
    const unsigned short* __restrict__ A, const float* __restrict__ Bf,
    float* __restrict__ C, int M, int N, int K) {
  int m0 = blockIdx.y * 128;
  int n0 = blockIdx.x * 128;
  __shared__ unsigned short As[128 * 40];
  __shared__ unsigned short Bs[128 * 40];
  int tid = threadIdx.x;
  int srow = tid >> 1;
  int scol = (tid & 1) * 16;
  const unsigned short* arow = A + (size_t)(m0 + srow) * K + scol;
  const float* browf = Bf + (size_t)(n0 + srow) * K + scol;
  unsigned short* As_w = As + srow * 40 + scol;
  unsigned short* Bs_w = Bs + srow * 40 + scol;
  int lane = tid & 63, wid = tid >> 6;
  int wr = wid >> 1, wc = wid & 1;
  int l15 = lane & 15, lg = lane >> 4;
  const unsigned short* Ar = As + ((wr * 64 + l15) * 40 + lg * 8);
  const unsigned short* Br = Bs + ((wc * 64 + l15) * 40 + lg * 8);
  f32x4 acc[4][4];
#pragma unroll
  for (int i = 0; i < 4; i++)
#pragma unroll
    for (int j = 0; j < 4; j++) acc[i][j] = (f32x4){0.f, 0.f, 0.f, 0.f};
  for (int k0 = 0; k0 < K; k0 += 32) {
    uint4 av0 = *(const uint4*)(arow + k0);
    uint4 av1 = *(const uint4*)(arow + k0 + 8);
    float4 f0 = *(const float4*)(browf + k0);
    float4 f1 = *(const float4*)(browf + k0 + 4);
    float4 f2 = *(const float4*)(browf + k0 + 8);
    float4 f3 = *(const float4*)(browf + k0 + 12);
    uint4 bv0 = make_uint4(pk2(f0.x, f0.y), pk2(f0.z, f0.w), pk2(f1.x, f1.y), pk2(f1.z, f1.w));
    uint4 bv1 = make_uint4(pk2(f2.x, f2.y), pk2(f2.z, f2.w), pk2(f3.x, f3.y), pk2(f3.z, f3.w));
    *(uint4*)As_w = av0; *(uint4*)(As_w + 8) = av1;
    *(uint4*)Bs_w = bv0; *(uint4*)(Bs_w + 8) = bv1;
    __syncthreads();
    bf16x8 af[4], bfr[4];
#pragma unroll
    for (int f = 0; f < 4; f++) {
      af[f]  = *(const bf16x8*)(Ar + f * 640);
      bfr[f] = *(const bf16x8*)(Br + f * 640);
    }
#pragma unroll
    for (int i = 0; i < 4; i++)
#pragma unroll
      for (int j = 0; j < 4; j++)
        acc[i][j] = __builtin_amdgcn_mfma_f32_16x16x32_bf16(af[i], bfr[j], acc[i][j], 0, 0, 0);
    __syncthreads();
  }
#pragma unroll
  for (int j = 0; j < 4; j++) {
    int n = n0 + wc * 64 + j * 16 + l15;
#pragma unroll
    for (int i = 0; i < 4; i++) {
      int mb = m0 + wr * 64 + i * 16 + lg * 4;
#pragma unroll
      for (int r = 0; r < 4; r++)
        C[(size_t)(mb + r) * N + n] = acc[i][j][r];
    }
  }
}

// ---------------- MoE scatter (bf16 path): x += w0*go[r0] + w1*go[r1] ----------------
__global__ __launch_bounds__(256) void k_scatter(const float* __restrict__ go,
    const int* __restrict__ rows, const float* __restrict__ tw, float* __restrict__ x) {
  int t = blockIdx.x;
  int r0 = rows[t * 2], r1 = rows[t * 2 + 1];
  float w0 = tw[t * 2], w1 = tw[t * 2 + 1];
  float* xr = x + (size_t)t * DD;
  const float* g0 = go + (size_t)r0 * DD;
  const float* g1 = go + (size_t)r1 * DD;
  for (int d = threadIdx.x; d < DD; d += 256)
    xr[d] += w0 * g0[d] + w1 * g1[d];
}

// ================= host =================
extern "C" void kernel_launch(void* const* d_in, const int* in_sizes, int n_in,
                              void* d_out, int out_size, void* d_ws, size_t ws_size,
                              hipStream_t stream) {
  (void)in_sizes; (void)n_in; (void)out_size;
  const int* tok   = (const int*)d_in[0];
  const float* emb = (const float*)d_in[1];
  const float* pos = (const float*)d_in[2];
  const float* wq  = (const float*)d_in[3];
  const float* bq  = (const float*)d_in[4];
  const float* wk  = (const float*)d_in[5];
  const float* bk  = (const float*)d_in[6];
  const float* wv  = (const float*)d_in[7];
  const float* bvv = (const float*)d_in[8];
  const float* wo  = (const float*)d_in[9];
  const float* bo  = (const float*)d_in[10];
  const float* ln1 = (const float*)d_in[11];
  const float* ln2 = (const float*)d_in[12];
  const float* gw  = (const float*)d_in[13];
  const float* gb  = (const float*)d_in[14];
  const float* w1  = (const float*)d_in[15];
  const float* b1  = (const float*)d_in[16];
  const float* w2  = (const float*)d_in[17];
  const float* b2  = (const float*)d_in[18];
  const float* lnf = (const float*)d_in[19];

  // ---- scratch carved from d_out (65.5M f32; all dead before lm_head) ----
  float* fp = (float*)d_out;
  float* qb   = fp; fp += (size_t)TT * DD;
  float* kb   = fp; fp += (size_t)TT * DD;
  float* vb   = fp; fp += (size_t)TT * DD;
  float* ao   = fp; fp += (size_t)TT * DD;
  float* x    = fp; fp += (size_t)TT * DD;
  float* h    = fp; fp += (size_t)TT * DD;
  float* gh1  = fp; fp += (size_t)TT * 2 * FF;      // f32, layer-1 experts
  float* go   = fp; fp += (size_t)TT * 2 * DD;
  float* glog = fp; fp += (size_t)TT * EE;
  float* tw   = fp; fp += (size_t)TT * 2;
  int* tidx   = (int*)fp; fp += TT * 2;
  int* rows   = (int*)fp; fp += TT * 2;
  int* gtok   = (int*)fp; fp += TT * 2;
  int* counts = (int*)fp; fp += 16;
  int* cursor = (int*)fp; fp += 16;
  int* bases  = (int*)fp; fp += 16;
  unsigned short* hb   = (unsigned short*)fp; fp += (size_t)TT * DD / 2;
  unsigned short* gh1b = (unsigned short*)fp; fp += (size_t)TT * 2 * FF / 2;
  unsigned short* w1t  = (unsigned short*)fp; fp += (size_t)EE * DD * FF / 2;  // layer-2 only
  unsigned short* w2t  = (unsigned short*)fp; fp += (size_t)EE * FF * DD / 2;
  float* part = fp; fp += (size_t)4 * 4096 * DD;    // split-K partials, 12.58M
  // total ~63.8M floats < 65.5M

  // d_ws: hf (bf16 final activations, must survive lm_head) + optional embT
  unsigned short* hf = (unsigned short*)d_ws;
  unsigned short* embT = (unsigned short*)d_ws + (size_t)TT * DD;
  bool useEmbT = ws_size >= (size_t)TT * DD * 2 + (size_t)VV * DD * 2;

  // ---- pre-pass ----
  k_embed<<<TT, 256, 0, stream>>>(tok, emb, pos, x);
  k_tcvt<<<dim3(96, 24, EE), 256, 0, stream>>>(w1 + (size_t)1 * EE * DD * FF, w1t,
      DD, FF, (size_t)DD * FF, (size_t)DD * FF);
  k_tcvt<<<dim3(24, 96, EE), 256, 0, stream>>>(w2 + (size_t)1 * EE * FF * DD, w2t,
      FF, DD, (size_t)FF * DD, (size_t)FF * DD);
  if (useEmbT)
    k_cvt<<<(VV * DD) / (256 * 8), 256, 0, stream>>>(emb, embT);

  for (int l = 0; l < NLAYER; l++) {
    const float* wq_l = wq + (size_t)l * DD * DD;
    const float* wk_l = wk + (size_t)l * DD * DD;
    const float* wv_l = wv + (size_t)l * DD * DD;
    const float* wo_l = wo + (size_t)l * DD * DD;

    // attention block (f32 — feeds routers)
    k_rmsnorm<<<TT, 256, 0, stream>>>(x, ln1 + (size_t)l * DD, h, hb);
    // QKV: split-K=2, 3 column-thirds
    k_skf32<false><<<dim3(18, 16, 2), 256, 0, stream>>>(h, wq_l, wk_l, wv_l,
        part, TT, 2304, 768, 768, 384, 2, TT, nullptr, nullptr);
    k_qkvred<<<TT, 256, 0, stream>>>(part, bq + (size_t)l * DD, bk + (size_t)l * DD,
        bvv + (size_t)l * DD, qb, kb, vb);
    k_attn<<<dim3(SS / QBLK, HH, BB), 256, 0, stream>>>(qb, kb, vb, ao);
    // O-proj: split-K=4
    k_skf32<false><<<dim3(6, 16, 4), 256, 0, stream>>>(ao, wo_l, wo_l, wo_l,
        part, TT, 768, 768, 768, 192, 4, TT, nullptr, nullptr);
    k_ored<<<TT, 256, 0, stream>>>(part, bo + (size_t)l * DD, x);

    // MoE block
    k_rmsnorm<<<TT, 256, 0, stream>>>(x, ln2 + (size_t)l * DD, h, hb);
    k_gate<<<TT, 256, 0, stream>>>(h, gw + (size_t)l * DD * EE, gb + (size_t)l * EE, glog);
    k_zero<<<1, 64, 0, stream>>>(counts, cursor);
    k_router<<<TT / 256, 256, 0, stream>>>(glog, tidx, tw, counts);
    k_scan<<<1, 1, 0, stream>>>(counts, bases, cursor);
    k_assign<<<TT / 256, 256, 0, stream>>>(tidx, cursor, rows, gtok);
    if (l < NLAYER - 1) {
      // feeds next layer's router -> f32 experts (R8-proven kernels)
      k_expert1<<<dim3(FF / 128, TT / 128, EE), 256, 0, stream>>>(
          h, w1 + (size_t)l * EE * DD * FF, b1 + (size_t)l * EE * FF,
          gtok, counts, bases, gh1);
      k_skf32<true><<<dim3(6, 16, 32), 256, 0, stream>>>(gh1,
          w2 + (size_t)l * EE * FF * DD, nullptr, nullptr,
          part, TT, 768, 768, FF, 768, 4, 4096, counts, bases);
      k_e2red<<<TT, 256, 0, stream>>>(part, rows, tidx, tw,
          b2 + (size_t)l * EE * DD, x);
    } else {
      // last layer: routing-irrelevant -> bf16 MFMA (gload_lds staging)
      k_mfma2<true, true, true, 2><<<dim3(FF / 128, TT / 128, EE), 256, 0, stream>>>(
          hb, w1t, b1 + (size_t)l * EE * FF, gh1b,
          TT, FF, DD, gtok, counts, bases);
      k_mfma2<true, false, true, 0><<<dim3(DD / 128, TT / 128, EE), 256, 0, stream>>>(
          gh1b, w2t, b2 + (size_t)l * EE * DD, go,
          TT, DD, FF, gtok, counts, bases);
      k_scatter<<<TT, 256, 0, stream>>>(go, rows, tw, x);
    }
  }

  // final norm + lm_head (bf16 MFMA)
  k_rmsnorm<<<TT, 256, 0, stream>>>(x, lnf, h, hf);
  if (useEmbT) {
    k_mfma2<false, false, false, 0><<<dim3(VV / 128, TT / 128), 256, 0, stream>>>(
        hf, embT, nullptr, (float*)d_out,
        TT, VV, DD, nullptr, nullptr, nullptr);
  } else {
    k_mfma_bf32<<<dim3(VV / 128, TT / 128), 256, 0, stream>>>(
        hf, emb, (float*)d_out, TT, VV, DD);
  }
}

// Round 11
// 2077.578 us; speedup vs baseline: 1.8062x; 1.0950x over previous
//
#include <hip/hip_runtime.h>
#include <math.h>

#define TT 2048      // B*S tokens
#define BB 2
#define SS 1024
#define DD 768
#define HH 12
#define FF 3072
#define EE 8
#define VV 32000
#define NLAYER 2
#define QBLK 8

typedef __attribute__((ext_vector_type(8))) short bf16x8;
typedef __attribute__((ext_vector_type(4))) float f32x4;

#define GL16(ldst, gsrc) __builtin_amdgcn_global_load_lds( \
    (const __attribute__((address_space(1))) void*)(gsrc), \
    (__attribute__((address_space(3))) void*)(ldst), 16, 0, 0)

static __device__ __forceinline__ unsigned short f2b(float f) {
  unsigned u = __float_as_uint(f);
  unsigned r = (u + 0x7fffu + ((u >> 16) & 1u)) >> 16;
  return (unsigned short)r;
}
static __device__ __forceinline__ unsigned int pk2(float a, float b) {
  return (unsigned int)f2b(a) | ((unsigned int)f2b(b) << 16);
}

// ---------------- embedding: x = emb[tok] + pos ----------------
__global__ __launch_bounds__(256) void k_embed(const int* __restrict__ tok,
    const float* __restrict__ emb, const float* __restrict__ pos,
    float* __restrict__ x) {
  int t = blockIdx.x;
  int s = t & (SS - 1);
  int tk = tok[t];
  const float* er = emb + (size_t)tk * DD;
  const float* pr = pos + (size_t)s * DD;
  float* xr = x + (size_t)t * DD;
  for (int d = threadIdx.x; d < DD; d += 256)
    xr[d] = er[d] + pr[d];
}

// ------------- rmsnorm: writes f32 out AND bf16 out -------------
__global__ __launch_bounds__(256) void k_rmsnorm(const float* __restrict__ x,
    const float* __restrict__ w, float* __restrict__ out,
    unsigned short* __restrict__ outb) {
  int t = blockIdx.x;
  const float* xr = x + (size_t)t * DD;
  int tid = threadIdx.x;
  float v0 = xr[tid], v1 = xr[tid + 256], v2 = xr[tid + 512];
  float ss = v0 * v0 + v1 * v1 + v2 * v2;
  for (int off = 32; off > 0; off >>= 1) ss += __shfl_down(ss, off, 64);
  __shared__ float ps[4];
  int wid = tid >> 6, lane = tid & 63;
  if (lane == 0) ps[wid] = ss;
  __syncthreads();
  float r = rsqrtf((ps[0] + ps[1] + ps[2] + ps[3]) * (1.0f / DD) + 1e-6f);
  float* orow = out + (size_t)t * DD;
  unsigned short* brow = outb + (size_t)t * DD;
  float o0 = v0 * r * w[tid], o1 = v1 * r * w[tid + 256], o2 = v2 * r * w[tid + 512];
  orow[tid] = o0; orow[tid + 256] = o1; orow[tid + 512] = o2;
  brow[tid] = f2b(o0); brow[tid + 256] = f2b(o1); brow[tid + 512] = f2b(o2);
}

// ------------- transpose+convert: f32 [R][C] -> bf16 [C][R] -------------
__global__ __launch_bounds__(256) void k_tcvt(const float* __restrict__ src,
    unsigned short* __restrict__ dst, int R, int C, size_t srcZ, size_t dstZ) {
  src += (size_t)blockIdx.z * srcZ;
  dst += (size_t)blockIdx.z * dstZ;
  __shared__ unsigned short tile[32][40];
  int t = threadIdx.x;
  int r = t >> 3, c4 = (t & 7) * 4;
  int r0 = blockIdx.y * 32, c0 = blockIdx.x * 32;
  float4 v = *(const float4*)(src + (size_t)(r0 + r) * C + c0 + c4);
  tile[r][c4 + 0] = f2b(v.x); tile[r][c4 + 1] = f2b(v.y);
  tile[r][c4 + 2] = f2b(v.z); tile[r][c4 + 3] = f2b(v.w);
  __syncthreads();
  int cc = t >> 3, r4 = (t & 7) * 4;
  ushort4 o;
  o.x = tile[r4 + 0][cc]; o.y = tile[r4 + 1][cc];
  o.z = tile[r4 + 2][cc]; o.w = tile[r4 + 3][cc];
  *(ushort4*)(dst + (size_t)(c0 + cc) * R + r0 + r4) = o;
}

// ------------- straight convert f32 -> bf16 (same layout) -------------
__global__ __launch_bounds__(256) void k_cvt(const float* __restrict__ src,
    unsigned short* __restrict__ dst) {
  size_t i = ((size_t)blockIdx.x * 256 + threadIdx.x) * 8;
  float4 a = *(const float4*)(src + i);
  float4 b = *(const float4*)(src + i + 4);
  ushort4 o0, o1;
  o0.x = f2b(a.x); o0.y = f2b(a.y); o0.z = f2b(a.z); o0.w = f2b(a.w);
  o1.x = f2b(b.x); o1.y = f2b(b.y); o1.z = f2b(b.z); o1.w = f2b(b.w);
  *(ushort4*)(dst + i) = o0;
  *(ushort4*)(dst + i + 4) = o1;
}

// ======== f32 split-K 128x128 GEMM, software-pipelined staging (R8-proven) ========
template<bool EXPERT>
__global__ __launch_bounds__(256) void k_skf32(
    const float* __restrict__ A, const float* __restrict__ W0,
    const float* __restrict__ W1, const float* __restrict__ W2,
    float* __restrict__ part, int M, int Ntot, int Nthird, int K, int KC,
    int nsplit, int prows,
    const int* __restrict__ counts, const int* __restrict__ bases) {
  int s, base = 0, cnt = M, sel = 0, n0;
  const float* W;
  if (EXPERT) {
    int z = blockIdx.z;
    s = z % nsplit;
    int e = z / nsplit;
    cnt = counts[e]; base = bases[e];
    W = W0 + (size_t)e * K * Nthird;
    n0 = blockIdx.x * 128;
  } else {
    s = blockIdx.z;
    int tpn = Nthird >> 7;
    sel = blockIdx.x / tpn;
    n0 = (blockIdx.x - sel * tpn) * 128;
    W = sel == 0 ? W0 : sel == 1 ? W1 : W2;
  }
  int m0 = blockIdx.y * 128;
  if (EXPERT && m0 >= cnt) return;
  int kbase = s * KC;

  __shared__ float As[16][132];   // k-major: As[k][m]
  __shared__ float Bs[16][132];
  int tid = threadIdx.x;
  int tx = tid & 15, ty = tid >> 4;
  int ra = tid >> 1, ka0 = (tid & 1) * 8;
  int kb = tid >> 4, nb0 = (tid & 15) * 8;
  bool arow_ok = !EXPERT || (m0 + ra < cnt);
  const float* Arow = A + (size_t)(EXPERT ? (base + m0 + (arow_ok ? ra : 0))
                                          : (m0 + ra)) * K + kbase;
  float acc[8][8] = {};

  // prologue: tile 0 -> regs
  float4 av0 = make_float4(0.f, 0.f, 0.f, 0.f), av1 = av0, bv0, bv1;
  if (arow_ok) {
    av0 = *(const float4*)(Arow + ka0);
    av1 = *(const float4*)(Arow + ka0 + 4);
  }
  {
    const float* Wrow = W + (size_t)(kbase + kb) * Nthird + n0 + nb0;
    bv0 = *(const float4*)(Wrow);
    bv1 = *(const float4*)(Wrow + 4);
  }

  for (int k0 = 0; k0 < KC; k0 += 16) {
    As[ka0 + 0][ra] = av0.x; As[ka0 + 1][ra] = av0.y;
    As[ka0 + 2][ra] = av0.z; As[ka0 + 3][ra] = av0.w;
    As[ka0 + 4][ra] = av1.x; As[ka0 + 5][ra] = av1.y;
    As[ka0 + 6][ra] = av1.z; As[ka0 + 7][ra] = av1.w;
    *(float4*)&Bs[kb][nb0] = bv0;
    *(float4*)&Bs[kb][nb0 + 4] = bv1;
    __syncthreads();
    float4 nav0 = make_float4(0.f, 0.f, 0.f, 0.f), nav1 = nav0, nbv0 = nav0, nbv1 = nav0;
    if (k0 + 16 < KC) {
      if (arow_ok) {
        nav0 = *(const float4*)(Arow + k0 + 16 + ka0);
        nav1 = *(const float4*)(Arow + k0 + 16 + ka0 + 4);
      }
      const float* Wn = W + (size_t)(kbase + k0 + 16 + kb) * Nthird + n0 + nb0;
      nbv0 = *(const float4*)(Wn);
      nbv1 = *(const float4*)(Wn + 4);
    }
#pragma unroll
    for (int kk = 0; kk < 16; kk++) {
      float4 a0 = *(const float4*)&As[kk][ty * 8];
      float4 a1 = *(const float4*)&As[kk][ty * 8 + 4];
      float4 b0 = *(const float4*)&Bs[kk][tx * 8];
      float4 b1 = *(const float4*)&Bs[kk][tx * 8 + 4];
      float a[8] = {a0.x, a0.y, a0.z, a0.w, a1.x, a1.y, a1.z, a1.w};
      float b[8] = {b0.x, b0.y, b0.z, b0.w, b1.x, b1.y, b1.z, b1.w};
#pragma unroll
      for (int i = 0; i < 8; i++) {
#pragma unroll
        for (int j = 0; j < 8; j++) acc[i][j] = fmaf(a[i], b[j], acc[i][j]);
      }
    }
    __syncthreads();
    av0 = nav0; av1 = nav1; bv0 = nbv0; bv1 = nbv1;
  }
#pragma unroll
  for (int i = 0; i < 8; i++) {
    int m = m0 + ty * 8 + i;
    if (EXPERT && m >= cnt) continue;
    size_t prow = EXPERT ? ((size_t)s * prows + base + m) : ((size_t)s * M + m);
    float* orow = part + prow * Ntot + sel * Nthird;
#pragma unroll
    for (int j = 0; j < 8; j++)
      orow[n0 + tx * 8 + j] = acc[i][j];
  }
}

// ---- QKV reduce: q/k/v = part0+part1 + bias ----
__global__ __launch_bounds__(256) void k_qkvred(const float* __restrict__ part,
    const float* __restrict__ bq, const float* __restrict__ bk,
    const float* __restrict__ bv, float* __restrict__ qb,
    float* __restrict__ kb, float* __restrict__ vb) {
  int t = blockIdx.x;
  for (int c = threadIdx.x; c < 2304; c += 256) {
    float v = part[(size_t)t * 2304 + c] + part[((size_t)TT + t) * 2304 + c];
    if (c < 768)       qb[(size_t)t * DD + c] = v + bq[c];
    else if (c < 1536) kb[(size_t)t * DD + c - 768] = v + bk[c - 768];
    else               vb[(size_t)t * DD + c - 1536] = v + bv[c - 1536];
  }
}

// ---- O-proj reduce: x += sum(part[0..3]) + bo ----
__global__ __launch_bounds__(256) void k_ored(const float* __restrict__ part,
    const float* __restrict__ bo, float* __restrict__ x) {
  int t = blockIdx.x;
  for (int d = threadIdx.x; d < DD; d += 256) {
    float v = part[(size_t)t * DD + d]
            + part[((size_t)TT + t) * DD + d]
            + part[((size_t)2 * TT + t) * DD + d]
            + part[((size_t)3 * TT + t) * DD + d];
    x[(size_t)t * DD + d] += v + bo[d];
  }
}

// ---- expert2 reduce + gate-weighted scatter: x += w*(sum(part)+b2) ----
__global__ __launch_bounds__(256) void k_e2red(const float* __restrict__ part,
    const int* __restrict__ rows, const int* __restrict__ tidx,
    const float* __restrict__ tw, const float* __restrict__ b2,
    float* __restrict__ x) {
  int t = blockIdx.x;
  int r0 = rows[t * 2], r1 = rows[t * 2 + 1];
  int e0 = tidx[t * 2], e1 = tidx[t * 2 + 1];
  float w0 = tw[t * 2], w1 = tw[t * 2 + 1];
  for (int d = threadIdx.x; d < DD; d += 256) {
    float v0 = part[(size_t)r0 * DD + d]
             + part[((size_t)4096 + r0) * DD + d]
             + part[((size_t)8192 + r0) * DD + d]
             + part[((size_t)12288 + r0) * DD + d] + b2[e0 * DD + d];
    float v1 = part[(size_t)r1 * DD + d]
             + part[((size_t)4096 + r1) * DD + d]
             + part[((size_t)8192 + r1) * DD + d]
             + part[((size_t)12288 + r1) * DD + d] + b2[e1 * DD + d];
    x[(size_t)t * DD + d] += w0 * v0 + w1 * v1;
  }
}

// ---------------- attention (f32); PV phase pairs qi (g, g+4) to share V loads ----
__global__ __launch_bounds__(256) void k_attn(const float* __restrict__ q,
    const float* __restrict__ k, const float* __restrict__ v, float* __restrict__ ao) {
  int b = blockIdx.z, hh = blockIdx.y, q0 = blockIdx.x * QBLK;
  __shared__ float qs[QBLK][64];
  __shared__ float sc[QBLK][SS];
  __shared__ float red[QBLK][8];
  int tid = threadIdx.x;
  const size_t hoff = (size_t)b * SS * DD + (size_t)hh * 64;
  for (int i = tid; i < QBLK * 64; i += 256) {
    int qi = i >> 6, d = i & 63;
    qs[qi][d] = q[hoff + (size_t)(q0 + qi) * DD + d];
  }
  __syncthreads();
  int kmax = q0 + QBLK;
  for (int j = tid; j < kmax; j += 256) {
    const float* kr = k + hoff + (size_t)j * DD;
    float p[QBLK];
#pragma unroll
    for (int qi = 0; qi < QBLK; qi++) p[qi] = 0.f;
#pragma unroll 4
    for (int c = 0; c < 16; c++) {
      float4 kv = *(const float4*)(kr + c * 4);
#pragma unroll
      for (int qi = 0; qi < QBLK; qi++)
        p[qi] += qs[qi][c * 4] * kv.x + qs[qi][c * 4 + 1] * kv.y +
                 qs[qi][c * 4 + 2] * kv.z + qs[qi][c * 4 + 3] * kv.w;
    }
#pragma unroll
    for (int qi = 0; qi < QBLK; qi++)
      sc[qi][j] = (j <= q0 + qi) ? p[qi] * 0.125f : -1e30f;
  }
  __syncthreads();
  int wid = tid >> 6, lane = tid & 63;
#pragma unroll
  for (int qi = 0; qi < QBLK; qi++) {
    float mx = -1e30f;
    for (int j = tid; j < kmax; j += 256) mx = fmaxf(mx, sc[qi][j]);
    for (int off = 32; off > 0; off >>= 1) mx = fmaxf(mx, __shfl_down(mx, off, 64));
    if (lane == 0) red[qi][wid] = mx;
  }
  __syncthreads();
#pragma unroll
  for (int qi = 0; qi < QBLK; qi++) {
    float mx = fmaxf(fmaxf(red[qi][0], red[qi][1]), fmaxf(red[qi][2], red[qi][3]));
    float s = 0.f;
    for (int j = tid; j < kmax; j += 256) {
      float e = __expf(sc[qi][j] - mx);
      sc[qi][j] = e;
      s += e;
    }
    for (int off = 32; off > 0; off >>= 1) s += __shfl_down(s, off, 64);
    if (lane == 0) red[qi][4 + wid] = s;
  }
  __syncthreads();
  // PV: group g handles qi=g and qi=g+4 in ONE j-loop (shared V load).
  // Chain assignment per qi is identical to the solo version -> bit-identical.
  int d = tid & 63, g = tid >> 6;
  {
    int qiA = g, qiB = g + 4;
    float invA = 1.f / (red[qiA][4] + red[qiA][5] + red[qiA][6] + red[qiA][7]);
    float invB = 1.f / (red[qiB][4] + red[qiB][5] + red[qiB][6] + red[qiB][7]);
    int jendA = q0 + qiA + 1;
    int jendB = q0 + qiB + 1;     // = jendA + 4
    const float* vp = v + hoff + d;
    float a0 = 0.f, a1 = 0.f, a2 = 0.f, a3 = 0.f;
    float b0 = 0.f, b1 = 0.f, b2 = 0.f, b3 = 0.f;
    int jA4 = jendA & ~3;
    for (int j = 0; j < jA4; j += 4) {
      float v0 = vp[(size_t)j * DD];
      float v1 = vp[(size_t)(j + 1) * DD];
      float v2 = vp[(size_t)(j + 2) * DD];
      float v3 = vp[(size_t)(j + 3) * DD];
      a0 = fmaf(sc[qiA][j],     v0, a0);
      a1 = fmaf(sc[qiA][j + 1], v1, a1);
      a2 = fmaf(sc[qiA][j + 2], v2, a2);
      a3 = fmaf(sc[qiA][j + 3], v3, a3);
      b0 = fmaf(sc[qiB][j],     v0, b0);
      b1 = fmaf(sc[qiB][j + 1], v1, b1);
      b2 = fmaf(sc[qiB][j + 2], v2, b2);
      b3 = fmaf(sc[qiB][j + 3], v3, b3);
    }
    for (int t = jA4; t < jendA; t++)
      a0 = fmaf(sc[qiA][t], vp[(size_t)t * DD], a0);
    // qiB's last full 4-group [jA4, jA4+4)
    b0 = fmaf(sc[qiB][jA4],     vp[(size_t)jA4 * DD], b0);
    b1 = fmaf(sc[qiB][jA4 + 1], vp[(size_t)(jA4 + 1) * DD], b1);
    b2 = fmaf(sc[qiB][jA4 + 2], vp[(size_t)(jA4 + 2) * DD], b2);
    b3 = fmaf(sc[qiB][jA4 + 3], vp[(size_t)(jA4 + 3) * DD], b3);
    for (int t = jA4 + 4; t < jendB; t++)
      b0 = fmaf(sc[qiB][t], vp[(size_t)t * DD], b0);
    float accA = (a0 + a2) + (a1 + a3);
    float accB = (b0 + b2) + (b1 + b3);
    ao[hoff + (size_t)(q0 + qiA) * DD + d] = accA * invA;
    ao[hoff + (size_t)(q0 + qiB) * DD + d] = accB * invB;
  }
}

// ---------------- gate logits ----------------
__global__ __launch_bounds__(256) void k_gate(const float* __restrict__ h,
    const float* __restrict__ gw, const float* __restrict__ gb,
    float* __restrict__ glog) {
  __shared__ float hr[DD];
  int t = blockIdx.x;
  for (int d = threadIdx.x; d < DD; d += 256) hr[d] = h[(size_t)t * DD + d];
  __syncthreads();
  int e = threadIdx.x >> 5, j = threadIdx.x & 31;
  float s = 0.f;
  for (int d = j; d < DD; d += 32) s += hr[d] * gw[d * EE + e];
  for (int off = 16; off > 0; off >>= 1) s += __shfl_down(s, off, 32);
  if (j == 0) glog[t * EE + e] = s + gb[e];
}

// ---------------- router ----------------
__global__ void k_zero(int* counts, int* cursor) {
  int i = threadIdx.x;
  if (i < EE) { counts[i] = 0; cursor[i] = 0; }
}

__global__ void k_router(const float* __restrict__ glog, int* __restrict__ tidx,
    float* __restrict__ tw, int* __restrict__ counts) {
  int t = blockIdx.x * 256 + threadIdx.x;
  if (t >= TT) return;
  float l[EE];
#pragma unroll
  for (int e = 0; e < EE; e++) l[e] = glog[t * EE + e];
  int i0 = 0; float v0 = l[0];
#pragma unroll
  for (int e = 1; e < EE; e++) if (l[e] > v0) { v0 = l[e]; i0 = e; }
  int i1 = -1; float v1 = -1e30f;
#pragma unroll
  for (int e = 0; e < EE; e++) if (e != i0 && l[e] > v1) { v1 = l[e]; i1 = e; }
  float e1 = __expf(v1 - v0);
  float inv = 1.f / (1.f + e1);
  tw[t * 2] = inv; tw[t * 2 + 1] = e1 * inv;
  tidx[t * 2] = i0; tidx[t * 2 + 1] = i1;
  atomicAdd(&counts[i0], 1);
  atomicAdd(&counts[i1], 1);
}

__global__ void k_scan(const int* __restrict__ counts, int* __restrict__ bases,
                       int* __restrict__ cursor) {
  int b = 0;
  for (int e = 0; e < EE; e++) { bases[e] = b; cursor[e] = b; b += counts[e]; }
}

__global__ void k_assign(const int* __restrict__ tidx, int* __restrict__ cursor,
                         int* __restrict__ rows, int* __restrict__ gtok) {
  int t = blockIdx.x * 256 + threadIdx.x;
  if (t >= TT) return;
#pragma unroll
  for (int kk = 0; kk < 2; kk++) {
    int e = tidx[t * 2 + kk];
    int r = atomicAdd(&cursor[e], 1);
    rows[t * 2 + kk] = r;
    gtok[r] = t;
  }
}

// ------- f32 expert FFN1, pipelined staging (R8-proven, feeds router) -------
__global__ __launch_bounds__(256) void k_expert1(const float* __restrict__ h,
    const float* __restrict__ w1, const float* __restrict__ b1,
    const int* __restrict__ gtok, const int* __restrict__ counts,
    const int* __restrict__ bases, float* __restrict__ gh1) {
  int e = blockIdx.z;
  int cnt = counts[e];
  int m0 = blockIdx.y * 128;
  if (m0 >= cnt) return;
  int base = bases[e];
  int n0 = blockIdx.x * 128;
  const float* W = w1 + (size_t)e * DD * FF;
  __shared__ float As[16][132];   // k-major
  __shared__ float Bs[16][132];
  int tid = threadIdx.x;
  int tx = tid & 15, ty = tid >> 4;
  int ra = tid >> 1, ka0 = (tid & 1) * 8;
  int kb = tid >> 4, nb0 = (tid & 15) * 8;
  int tok = (m0 + ra < cnt) ? gtok[base + m0 + ra] : -1;
  const float* Arow = h + (size_t)(tok < 0 ? 0 : tok) * DD;
  float acc[8][8] = {};

  float4 av0 = make_float4(0.f, 0.f, 0.f, 0.f), av1 = av0, bv0, bv1;
  if (tok >= 0) {
    av0 = *(const float4*)(Arow + ka0);
    av1 = *(const float4*)(Arow + ka0 + 4);
  }
  {
    const float* Wrow = W + (size_t)kb * FF + n0 + nb0;
    bv0 = *(const float4*)(Wrow);
    bv1 = *(const float4*)(Wrow + 4);
  }

  for (int k0 = 0; k0 < DD; k0 += 16) {
    As[ka0 + 0][ra] = av0.x; As[ka0 + 1][ra] = av0.y;
    As[ka0 + 2][ra] = av0.z; As[ka0 + 3][ra] = av0.w;
    As[ka0 + 4][ra] = av1.x; As[ka0 + 5][ra] = av1.y;
    As[ka0 + 6][ra] = av1.z; As[ka0 + 7][ra] = av1.w;
    *(float4*)&Bs[kb][nb0] = bv0;
    *(float4*)&Bs[kb][nb0 + 4] = bv1;
    __syncthreads();
    float4 nav0 = make_float4(0.f, 0.f, 0.f, 0.f), nav1 = nav0, nbv0 = nav0, nbv1 = nav0;
    if (k0 + 16 < DD) {
      if (tok >= 0) {
        nav0 = *(const float4*)(Arow + k0 + 16 + ka0);
        nav1 = *(const float4*)(Arow + k0 + 16 + ka0 + 4);
      }
      const float* Wn = W + (size_t)(k0 + 16 + kb) * FF + n0 + nb0;
      nbv0 = *(const float4*)(Wn);
      nbv1 = *(const float4*)(Wn + 4);
    }
#pragma unroll
    for (int kk = 0; kk < 16; kk++) {
      float4 a0 = *(const float4*)&As[kk][ty * 8];
      float4 a1 = *(const float4*)&As[kk][ty * 8 + 4];
      float4 b0 = *(const float4*)&Bs[kk][tx * 8];
      float4 b1 = *(const float4*)&Bs[kk][tx * 8 + 4];
      float a[8] = {a0.x, a0.y, a0.z, a0.w, a1.x, a1.y, a1.z, a1.w};
      float b[8] = {b0.x, b0.y, b0.z, b0.w, b1.x, b1.y, b1.z, b1.w};
#pragma unroll
      for (int i = 0; i < 8; i++) {
#pragma unroll
        for (int j = 0; j < 8; j++) acc[i][j] = fmaf(a[i], b[j], acc[i][j]);
      }
    }
    __syncthreads();
    av0 = nav0; av1 = nav1; bv0 = nbv0; bv1 = nbv1;
  }
#pragma unroll
  for (int i = 0; i < 8; i++) {
    int m = m0 + ty * 8 + i;
    if (m >= cnt) continue;
    float* orow = gh1 + (size_t)(base + m) * FF;
#pragma unroll
    for (int j = 0; j < 8; j++) {
      int n = n0 + tx * 8 + j;
      float vv = acc[i][j] + b1[e * FF + n];
      orow[n] = 0.5f * vv * (1.f + erff(vv * 0.70710678118654752f));
    }
  }
}

// ===== bf16 MFMA GEMM, m97-style global_load_lds staging (linear LDS) =====
// EPI: 0 = store f32 (+bias), 2 = gelu -> bf16 (+bias).
template<bool EXPERT, bool GATHER, bool BIAS, int EPI>
__global__ __launch_bounds__(256) void k_mfma2(
    const unsigned short* __restrict__ A, const unsigned short* __restrict__ Bt,
    const float* __restrict__ bias, void* __restrict__ Cv,
    int M, int N, int K,
    const int* __restrict__ gtok, const int* __restrict__ counts,
    const int* __restrict__ bases) {
  int cnt = M, base = 0;
  if (EXPERT) {
    int e = blockIdx.z;
    cnt = counts[e]; base = bases[e];
    if (BIAS) bias += (size_t)e * N;
    Bt += (size_t)e * N * K;
  }
  int m0 = blockIdx.y * 128;
  if (EXPERT && m0 >= cnt) return;
  int n0 = blockIdx.x * 128;

  __shared__ unsigned short As[128 * 32];   // linear [row][32k], 64B rows
  __shared__ unsigned short Bs[128 * 32];

  int tid = threadIdx.x, lane = tid & 63, w = tid >> 6;
  int r0 = w * 16 + (lane >> 2);            // staging row, issue 0 (0..63)
  int r1 = 64 + r0;                          // issue 1 (64..127)
  int kc = (lane & 3) * 8;                   // k-offset (elements)

  const unsigned short *pA0, *pA1;
  if (GATHER) {
    int t0 = (m0 + r0 < cnt) ? gtok[base + m0 + r0] : 0;
    int t1 = (m0 + r1 < cnt) ? gtok[base + m0 + r1] : 0;
    pA0 = A + (size_t)t0 * K + kc;
    pA1 = A + (size_t)t1 * K + kc;
  } else if (EXPERT) {
    int q0_ = (m0 + r0 < cnt) ? base + m0 + r0 : base;
    int q1_ = (m0 + r1 < cnt) ? base + m0 + r1 : base;
    pA0 = A + (size_t)q0_ * K + kc;
    pA1 = A + (size_t)q1_ * K + kc;
  } else {
    pA0 = A + (size_t)(m0 + r0) * K + kc;
    pA1 = A + (size_t)(m0 + r1) * K + kc;
  }
  const unsigned short* pB0 = Bt + (size_t)(n0 + r0) * K + kc;
  const unsigned short* pB1 = Bt + (size_t)(n0 + r1) * K + kc;

  unsigned short* dA0 = As + w * 512;        // wave-uniform LDS bases
  unsigned short* dA1 = As + 2048 + w * 512;
  unsigned short* dB0 = Bs + w * 512;
  unsigned short* dB1 = Bs + 2048 + w * 512;

  int wr = w >> 1, wc = w & 1;
  int l15 = lane & 15, lg = lane >> 4;
  const unsigned short* Ar = As + ((wr * 64 + l15) * 32 + lg * 8);
  const unsigned short* Br = Bs + ((wc * 64 + l15) * 32 + lg * 8);

  f32x4 acc[4][4];
#pragma unroll
  for (int i = 0; i < 4; i++)
#pragma unroll
    for (int j = 0; j < 4; j++) acc[i][j] = (f32x4){0.f, 0.f, 0.f, 0.f};

  for (int k0 = 0; k0 < K; k0 += 32) {
    GL16(dA0, pA0 + k0);
    GL16(dA1, pA1 + k0);
    GL16(dB0, pB0 + k0);
    GL16(dB1, pB1 + k0);
    __syncthreads();
    bf16x8 af[4], bfr[4];
#pragma unroll
    for (int f = 0; f < 4; f++) {
      af[f]  = *(const bf16x8*)(Ar + f * 512);
      bfr[f] = *(const bf16x8*)(Br + f * 512);
    }
#pragma unroll
    for (int i = 0; i < 4; i++)
#pragma unroll
      for (int j = 0; j < 4; j++)
        acc[i][j] = __builtin_amdgcn_mfma_f32_16x16x32_bf16(af[i], bfr[j], acc[i][j], 0, 0, 0);
    __syncthreads();
  }

#pragma unroll
  for (int j = 0; j < 4; j++) {
    int n = n0 + wc * 64 + j * 16 + l15;
    float bb = BIAS ? bias[n] : 0.f;
#pragma unroll
    for (int i = 0; i < 4; i++) {
      int mb = m0 + wr * 64 + i * 16 + lg * 4;
#pragma unroll
      for (int r = 0; r < 4; r++) {
        int m = mb + r;
        if (EXPERT && m >= cnt) continue;
        size_t off = (size_t)(base + m) * N + n;
        float v = acc[i][j][r] + bb;
        if (EPI == 0) {
          ((float*)Cv)[off] = v;
        } else {
          float g = 0.5f * v * (1.f + erff(v * 0.70710678118654752f));
          ((unsigned short*)Cv)[off] = f2b(g);
        }
      }
    }
  }
}

// ===== bf16 MFMA GEMM, register-staged, B from f32 (lm_head tail tiles) =====
__global__ __launch_bounds__(256) void k_mfma_bf32(
    const unsigned short* __restrict__ A, const float* __restrict__ Bf,
    float* __restrict__ C, int M, int N, int K, int mtile0) {
  int m0 = (blockIdx.y + mtile0) * 128;
  int n0 = blockIdx.x * 128;
  __shared__ unsigned short As[128 * 40];
  __shared__ unsigned short Bs[128 * 40];
  int tid = threadIdx.x;
  int srow = tid >> 1;
  int scol = (tid & 1) * 16;
  const unsigned short* arow = A + (size_t)(m0 + srow) * K + scol;
  const float* browf = Bf + (size_t)(n0 + srow) * K + scol;
  unsigned short* As_w = As + srow * 40 + scol;
  unsigned short* Bs_w = Bs + srow * 40 + scol;
  int lane = tid & 63, wid = tid >> 6;
  int wr = wid >> 1, wc = wid & 1;
  int l15 = lane & 15, lg = lane >> 4;
  const unsigned short* Ar = As + ((wr * 64 + l15) * 40 + lg * 8);
  const unsigned short* Br = Bs + ((wc * 64 + l15) * 40 + lg * 8);
  f32x4 acc[4][4];
#pragma unroll
  for (int i = 0; i < 4; i++)
#pragma unroll
    for (int j = 0; j < 4; j++) acc[i][j] = (f32x4){0.f, 0.f, 0.f, 0.f};
  for (int k0 = 0; k0 < K; k0 += 32) {
    uint4 av0 = *(const uint4*)(arow + k0);
    uint4 av1 = *(const uint4*)(arow + k0 + 8);
    float4 f0 = *(const float4*)(browf + k0);
    float4 f1 = *(const float4*)(browf + k0 + 4);
    float4 f2 = *(const float4*)(browf + k0 + 8);
    float4 f3 = *(const float4*)(browf + k0 + 12);
    uint4 bv0 = make_uint4(pk2(f0.x, f0.y), pk2(f0.z, f0.w), pk2(f1.x, f1.y), pk2(f1.z, f1.w));
    uint4 bv1 = make_uint4(pk2(f2.x, f2.y), pk2(f2.z, f2.w), pk2(f3.x, f3.y), pk2(f3.z, f3.w));
    *(uint4*)As_w = av0; *(uint4*)(As_w + 8) = av1;
    *(uint4*)Bs_w = bv0; *(uint4*)(Bs_w + 8) = bv1;
    __syncthreads();
    bf16x8 af[4], bfr[4];
#pragma unroll
    for (int f = 0; f < 4; f++) {
      af[f]  = *(const bf16x8*)(Ar + f * 640);
      bfr[f] = *(const bf16x8*)(Br + f * 640);
    }
#pragma unroll
    for (int i = 0; i < 4; i++)
#pragma unroll
      for (int j = 0; j < 4; j++)
        acc[i][j] = __builtin_amdgcn_mfma_f32_16x16x32_bf16(af[i], bfr[j], acc[i][j], 0, 0, 0);
    __syncthreads();
  }
#pragma unroll
  for (int j = 0; j < 4; j++) {
    int n = n0 + wc * 64 + j * 16 + l15;
#pragma unroll
    for (int i = 0; i < 4; i++) {
      int mb = m0 + wr * 64 + i * 16 + lg * 4;
#pragma unroll
      for (int r = 0; r < 4; r++)
        C[(size_t)(mb + r) * N + n] = acc[i][j][r];
    }
  }
}

// ---------------- MoE scatter (bf16 path): x += w0*go[r0] + w1*go[r1] ----------------
__global__ __launch_bounds__(256) void k_scatter(const float* __restrict__ go,
    const int* __restrict__ rows, const float* __restrict__ tw, float* __restrict__ x) {
  int t = blockIdx.x;
  int r0 = rows[t * 2], r1 = rows[t * 2 + 1];
  float w0 = tw[t * 2], w1 = tw[t * 2 + 1];
  float* xr = x + (size_t)t * DD;
  const float* g0 = go + (size_t)r0 * DD;
  const float* g1 = go + (size_t)r1 * DD;
  for (int d = threadIdx.x; d < DD; d += 256)
    xr[d] += w0 * g0[d] + w1 * g1[d];
}

// ================= host =================
extern "C" void kernel_launch(void* const* d_in, const int* in_sizes, int n_in,
                              void* d_out, int out_size, void* d_ws, size_t ws_size,
                              hipStream_t stream) {
  (void)in_sizes; (void)n_in; (void)out_size;
  const int* tok   = (const int*)d_in[0];
  const float* emb = (const float*)d_in[1];
  const float* pos = (const float*)d_in[2];
  const float* wq  = (const float*)d_in[3];
  const float* bq  = (const float*)d_in[4];
  const float* wk  = (const float*)d_in[5];
  const float* bk  = (const float*)d_in[6];
  const float* wv  = (const float*)d_in[7];
  const float* bvv = (const float*)d_in[8];
  const float* wo  = (const float*)d_in[9];
  const float* bo  = (const float*)d_in[10];
  const float* ln1 = (const float*)d_in[11];
  const float* ln2 = (const float*)d_in[12];
  const float* gw  = (const float*)d_in[13];
  const float* gb  = (const float*)d_in[14];
  const float* w1  = (const float*)d_in[15];
  const float* b1  = (const float*)d_in[16];
  const float* w2  = (const float*)d_in[17];
  const float* b2  = (const float*)d_in[18];
  const float* lnf = (const float*)d_in[19];

  // ---- scratch carved from d_out (65.5M f32; all dead before lm_head) ----
  float* ob = (float*)d_out;
  float* fp = ob;
  float* qb   = fp; fp += (size_t)TT * DD;
  float* kb   = fp; fp += (size_t)TT * DD;
  float* vb   = fp; fp += (size_t)TT * DD;
  float* ao   = fp; fp += (size_t)TT * DD;
  float* x    = fp; fp += (size_t)TT * DD;
  float* h    = fp; fp += (size_t)TT * DD;
  float* gh1  = fp; fp += (size_t)TT * 2 * FF;      // f32, layer-1 experts
  float* go   = fp; fp += (size_t)TT * 2 * DD;
  float* glog = fp; fp += (size_t)TT * EE;
  float* tw   = fp; fp += (size_t)TT * 2;
  int* tidx   = (int*)fp; fp += TT * 2;
  int* rows   = (int*)fp; fp += TT * 2;
  int* gtok   = (int*)fp; fp += TT * 2;
  int* counts = (int*)fp; fp += 16;
  int* cursor = (int*)fp; fp += 16;
  int* bases  = (int*)fp; fp += 16;
  unsigned short* hb   = (unsigned short*)fp; fp += (size_t)TT * DD / 2;
  unsigned short* gh1b = (unsigned short*)fp; fp += (size_t)TT * 2 * FF / 2;
  unsigned short* w1t  = (unsigned short*)fp; fp += (size_t)EE * DD * FF / 2;  // layer-2 only
  unsigned short* w2t  = (unsigned short*)fp; fp += (size_t)EE * FF * DD / 2;
  float* part = fp; fp += (size_t)4 * 4096 * DD;    // split-K partials, 12.58M
  // total ~63.8M floats < 65.5M

  // hf (bf16 final activations, must survive lm_head) -> d_ws
  unsigned short* hf = (unsigned short*)d_ws;
  // embT (bf16 lm_head B): d_ws if it fits, else arena tail = output rows >= 1664
  // (float offset 53,248,000 = row 1664 exactly; dead after layer-1 O-reduce)
  bool useWs = ws_size >= (size_t)TT * DD * 2 + (size_t)VV * DD * 2;
  unsigned short* embT = useWs ? (unsigned short*)d_ws + (size_t)TT * DD
                               : (unsigned short*)(ob + 53248000ull);

  // ---- pre-pass ----
  k_embed<<<TT, 256, 0, stream>>>(tok, emb, pos, x);
  k_tcvt<<<dim3(96, 24, EE), 256, 0, stream>>>(w1 + (size_t)1 * EE * DD * FF, w1t,
      DD, FF, (size_t)DD * FF, (size_t)DD * FF);
  k_tcvt<<<dim3(24, 96, EE), 256, 0, stream>>>(w2 + (size_t)1 * EE * FF * DD, w2t,
      FF, DD, (size_t)FF * DD, (size_t)FF * DD);

  for (int l = 0; l < NLAYER; l++) {
    const float* wq_l = wq + (size_t)l * DD * DD;
    const float* wk_l = wk + (size_t)l * DD * DD;
    const float* wv_l = wv + (size_t)l * DD * DD;
    const float* wo_l = wo + (size_t)l * DD * DD;

    // attention block (f32 — feeds routers)
    k_rmsnorm<<<TT, 256, 0, stream>>>(x, ln1 + (size_t)l * DD, h, hb);
    // QKV: split-K=2, 3 column-thirds
    k_skf32<false><<<dim3(18, 16, 2), 256, 0, stream>>>(h, wq_l, wk_l, wv_l,
        part, TT, 2304, 768, 768, 384, 2, TT, nullptr, nullptr);
    k_qkvred<<<TT, 256, 0, stream>>>(part, bq + (size_t)l * DD, bk + (size_t)l * DD,
        bvv + (size_t)l * DD, qb, kb, vb);
    k_attn<<<dim3(SS / QBLK, HH, BB), 256, 0, stream>>>(qb, kb, vb, ao);
    // O-proj: split-K=4
    k_skf32<false><<<dim3(6, 16, 4), 256, 0, stream>>>(ao, wo_l, wo_l, wo_l,
        part, TT, 768, 768, 768, 192, 4, TT, nullptr, nullptr);
    k_ored<<<TT, 256, 0, stream>>>(part, bo + (size_t)l * DD, x);

    // MoE block
    k_rmsnorm<<<TT, 256, 0, stream>>>(x, ln2 + (size_t)l * DD, h, hb);
    k_gate<<<TT, 256, 0, stream>>>(h, gw + (size_t)l * DD * EE, gb + (size_t)l * EE, glog);
    k_zero<<<1, 64, 0, stream>>>(counts, cursor);
    k_router<<<TT / 256, 256, 0, stream>>>(glog, tidx, tw, counts);
    k_scan<<<1, 1, 0, stream>>>(counts, bases, cursor);
    k_assign<<<TT / 256, 256, 0, stream>>>(tidx, cursor, rows, gtok);
    if (l < NLAYER - 1) {
      // feeds next layer's router -> f32 experts (R8-proven kernels)
      k_expert1<<<dim3(FF / 128, TT / 128, EE), 256, 0, stream>>>(
          h, w1 + (size_t)l * EE * DD * FF, b1 + (size_t)l * EE * FF,
          gtok, counts, bases, gh1);
      k_skf32<true><<<dim3(6, 16, 32), 256, 0, stream>>>(gh1,
          w2 + (size_t)l * EE * FF * DD, nullptr, nullptr,
          part, TT, 768, 768, FF, 768, 4, 4096, counts, bases);
      k_e2red<<<TT, 256, 0, stream>>>(part, rows, tidx, tw,
          b2 + (size_t)l * EE * DD, x);
    } else {
      // last layer: routing-irrelevant -> bf16 MFMA (gload_lds staging)
      k_mfma2<true, true, true, 2><<<dim3(FF / 128, TT / 128, EE), 256, 0, stream>>>(
          hb, w1t, b1 + (size_t)l * EE * FF, gh1b,
          TT, FF, DD, gtok, counts, bases);
      k_mfma2<true, false, true, 0><<<dim3(DD / 128, TT / 128, EE), 256, 0, stream>>>(
          gh1b, w2t, b2 + (size_t)l * EE * DD, go,
          TT, DD, FF, gtok, counts, bases);
      k_scatter<<<TT, 256, 0, stream>>>(go, rows, tw, x);
    }
  }

  // embT conversion (part region is dead now; same-stream ordering makes it safe)
  k_cvt<<<(VV * DD) / (256 * 8), 256, 0, stream>>>(emb, embT);
  // final norm + lm_head (bf16 MFMA)
  k_rmsnorm<<<TT, 256, 0, stream>>>(x, lnf, h, hf);
  if (useWs) {
    k_mfma2<false, false, false, 0><<<dim3(VV / 128, 16), 256, 0, stream>>>(
        hf, embT, nullptr, (float*)d_out,
        TT, VV, DD, nullptr, nullptr, nullptr);
  } else {
    // phase 1: rows 0..1663 read embT (rows >= 1664) — disjoint, race-free
    k_mfma2<false, false, false, 0><<<dim3(VV / 128, 13), 256, 0, stream>>>(
        hf, embT, nullptr, (float*)d_out,
        TT, VV, DD, nullptr, nullptr, nullptr);
    // phase 2: rows 1664..2047 (overwrites embT), B staged from f32 emb
    k_mfma_bf32<<<dim3(VV / 128, 3), 256, 0, stream>>>(
        hf, emb, (float*)d_out, TT, VV, DD, 13);
  }
}

// Round 12
// 1987.985 us; speedup vs baseline: 1.8876x; 1.0451x over previous
//
#include <hip/hip_runtime.h>
#include <math.h>

#define TT 2048      // B*S tokens
#define BB 2
#define SS 1024
#define DD 768
#define HH 12
#define FF 3072
#define EE 8
#define VV 32000
#define NLAYER 2
#define QBLK 8

typedef __attribute__((ext_vector_type(8))) short bf16x8;
typedef __attribute__((ext_vector_type(4))) float f32x4;

#define GL16(ldst, gsrc) __builtin_amdgcn_global_load_lds( \
    (const __attribute__((address_space(1))) void*)(gsrc), \
    (__attribute__((address_space(3))) void*)(ldst), 16, 0, 0)

static __device__ __forceinline__ unsigned short f2b(float f) {
  unsigned u = __float_as_uint(f);
  unsigned r = (u + 0x7fffu + ((u >> 16) & 1u)) >> 16;
  return (unsigned short)r;
}
static __device__ __forceinline__ unsigned int pk2(float a, float b) {
  return (unsigned int)f2b(a) | ((unsigned int)f2b(b) << 16);
}

// ---- shared rmsnorm tail: v0..v2 are x[tid], x[tid+256], x[tid+512] ----
// (reduction order identical to the original standalone k_rmsnorm)
static __device__ __forceinline__ float rms_scale(float v0, float v1, float v2,
                                                  float* ps, int tid) {
  float ss = v0 * v0 + v1 * v1 + v2 * v2;
  for (int off = 32; off > 0; off >>= 1) ss += __shfl_down(ss, off, 64);
  int wid = tid >> 6, lane = tid & 63;
  if (lane == 0) ps[wid] = ss;
  __syncthreads();
  return rsqrtf((ps[0] + ps[1] + ps[2] + ps[3]) * (1.0f / DD) + 1e-6f);
}

// ---------------- embed + rmsnorm(ln1 L0) ----------------
__global__ __launch_bounds__(256) void k_embed_rms(const int* __restrict__ tok,
    const float* __restrict__ emb, const float* __restrict__ pos,
    const float* __restrict__ w, float* __restrict__ x,
    float* __restrict__ h, unsigned short* __restrict__ hb) {
  int t = blockIdx.x;
  int s = t & (SS - 1);
  int tk = tok[t];
  const float* er = emb + (size_t)tk * DD;
  const float* pr = pos + (size_t)s * DD;
  int tid = threadIdx.x;
  float v0 = er[tid] + pr[tid];
  float v1 = er[tid + 256] + pr[tid + 256];
  float v2 = er[tid + 512] + pr[tid + 512];
  float* xr = x + (size_t)t * DD;
  xr[tid] = v0; xr[tid + 256] = v1; xr[tid + 512] = v2;
  __shared__ float ps[4];
  float r = rms_scale(v0, v1, v2, ps, tid);
  float o0 = v0 * r * w[tid], o1 = v1 * r * w[tid + 256], o2 = v2 * r * w[tid + 512];
  float* orow = h + (size_t)t * DD;
  unsigned short* brow = hb + (size_t)t * DD;
  orow[tid] = o0; orow[tid + 256] = o1; orow[tid + 512] = o2;
  brow[tid] = f2b(o0); brow[tid + 256] = f2b(o1); brow[tid + 512] = f2b(o2);
}

// ---- O-reduce + residual + rmsnorm(ln2) + gate logits ----
__global__ __launch_bounds__(256) void k_ored_rms_gate(const float* __restrict__ part,
    const float* __restrict__ bo, const float* __restrict__ w,
    const float* __restrict__ gw, const float* __restrict__ gb,
    float* __restrict__ x, float* __restrict__ h, unsigned short* __restrict__ hb,
    float* __restrict__ glog) {
  int t = blockIdx.x;
  int tid = threadIdx.x;
  float* xr = x + (size_t)t * DD;
  float v[3];
#pragma unroll
  for (int i = 0; i < 3; i++) {
    int d = tid + i * 256;
    float s = part[(size_t)t * DD + d]
            + part[((size_t)TT + t) * DD + d]
            + part[((size_t)2 * TT + t) * DD + d]
            + part[((size_t)3 * TT + t) * DD + d];
    float xn = xr[d] + (s + bo[d]);   // identical to k_ored: x += v + bo
    xr[d] = xn;
    v[i] = xn;
  }
  __shared__ float ps[4];
  __shared__ float hr[DD];
  float r = rms_scale(v[0], v[1], v[2], ps, tid);
  float* orow = h + (size_t)t * DD;
  unsigned short* brow = hb + (size_t)t * DD;
#pragma unroll
  for (int i = 0; i < 3; i++) {
    int d = tid + i * 256;
    float o = v[i] * r * w[d];
    orow[d] = o; brow[d] = f2b(o); hr[d] = o;
  }
  __syncthreads();
  // gate: identical structure to the standalone k_gate
  int e = tid >> 5, j = tid & 31;
  float s = 0.f;
  for (int d = j; d < DD; d += 32) s += hr[d] * gw[d * EE + e];
  for (int off = 16; off > 0; off >>= 1) s += __shfl_down(s, off, 32);
  if (j == 0) glog[t * EE + e] = s + gb[e];
}

// ---- expert2-reduce + weighted scatter + rmsnorm(ln1 of next layer) ----
__global__ __launch_bounds__(256) void k_e2red_rms(const float* __restrict__ part,
    const int* __restrict__ rows, const int* __restrict__ tidx,
    const float* __restrict__ tw, const float* __restrict__ b2,
    const float* __restrict__ w, float* __restrict__ x,
    float* __restrict__ h, unsigned short* __restrict__ hb) {
  int t = blockIdx.x;
  int r0 = rows[t * 2], r1 = rows[t * 2 + 1];
  int e0 = tidx[t * 2], e1 = tidx[t * 2 + 1];
  float w0 = tw[t * 2], w1 = tw[t * 2 + 1];
  int tid = threadIdx.x;
  float* xr = x + (size_t)t * DD;
  float v[3];
#pragma unroll
  for (int i = 0; i < 3; i++) {
    int d = tid + i * 256;
    float v0 = part[(size_t)r0 * DD + d]
             + part[((size_t)4096 + r0) * DD + d]
             + part[((size_t)8192 + r0) * DD + d]
             + part[((size_t)12288 + r0) * DD + d] + b2[e0 * DD + d];
    float v1 = part[(size_t)r1 * DD + d]
             + part[((size_t)4096 + r1) * DD + d]
             + part[((size_t)8192 + r1) * DD + d]
             + part[((size_t)12288 + r1) * DD + d] + b2[e1 * DD + d];
    float xn = xr[d] + (w0 * v0 + w1 * v1);   // identical to k_e2red
    xr[d] = xn;
    v[i] = xn;
  }
  __shared__ float ps[4];
  float r = rms_scale(v[0], v[1], v[2], ps, tid);
  float* orow = h + (size_t)t * DD;
  unsigned short* brow = hb + (size_t)t * DD;
#pragma unroll
  for (int i = 0; i < 3; i++) {
    int d = tid + i * 256;
    float o = v[i] * r * w[d];
    orow[d] = o; brow[d] = f2b(o);
  }
}

// ---- L2 scatter + rmsnorm(lnf) -> hf (bf16 only) ----
__global__ __launch_bounds__(256) void k_scatter_rms(const float* __restrict__ go,
    const int* __restrict__ rows, const float* __restrict__ tw,
    const float* __restrict__ w, const float* __restrict__ x,
    unsigned short* __restrict__ hf) {
  int t = blockIdx.x;
  int r0 = rows[t * 2], r1 = rows[t * 2 + 1];
  float w0 = tw[t * 2], w1 = tw[t * 2 + 1];
  int tid = threadIdx.x;
  const float* xr = x + (size_t)t * DD;
  const float* g0 = go + (size_t)r0 * DD;
  const float* g1 = go + (size_t)r1 * DD;
  float v[3];
#pragma unroll
  for (int i = 0; i < 3; i++) {
    int d = tid + i * 256;
    v[i] = xr[d] + (w0 * g0[d] + w1 * g1[d]);   // identical to k_scatter
  }
  __shared__ float ps[4];
  float r = rms_scale(v[0], v[1], v[2], ps, tid);
  unsigned short* brow = hf + (size_t)t * DD;
#pragma unroll
  for (int i = 0; i < 3; i++) {
    int d = tid + i * 256;
    brow[d] = f2b(v[i] * r * w[d]);
  }
}

// ------------- transpose+convert: f32 [R][C] -> bf16 [C][R] -------------
__global__ __launch_bounds__(256) void k_tcvt(const float* __restrict__ src,
    unsigned short* __restrict__ dst, int R, int C, size_t srcZ, size_t dstZ) {
  src += (size_t)blockIdx.z * srcZ;
  dst += (size_t)blockIdx.z * dstZ;
  __shared__ unsigned short tile[32][40];
  int t = threadIdx.x;
  int r = t >> 3, c4 = (t & 7) * 4;
  int r0 = blockIdx.y * 32, c0 = blockIdx.x * 32;
  float4 v = *(const float4*)(src + (size_t)(r0 + r) * C + c0 + c4);
  tile[r][c4 + 0] = f2b(v.x); tile[r][c4 + 1] = f2b(v.y);
  tile[r][c4 + 2] = f2b(v.z); tile[r][c4 + 3] = f2b(v.w);
  __syncthreads();
  int cc = t >> 3, r4 = (t & 7) * 4;
  ushort4 o;
  o.x = tile[r4 + 0][cc]; o.y = tile[r4 + 1][cc];
  o.z = tile[r4 + 2][cc]; o.w = tile[r4 + 3][cc];
  *(ushort4*)(dst + (size_t)(c0 + cc) * R + r0 + r4) = o;
}

// ------------- straight convert f32 -> bf16 (same layout) -------------
__global__ __launch_bounds__(256) void k_cvt(const float* __restrict__ src,
    unsigned short* __restrict__ dst) {
  size_t i = ((size_t)blockIdx.x * 256 + threadIdx.x) * 8;
  float4 a = *(const float4*)(src + i);
  float4 b = *(const float4*)(src + i + 4);
  ushort4 o0, o1;
  o0.x = f2b(a.x); o0.y = f2b(a.y); o0.z = f2b(a.z); o0.w = f2b(a.w);
  o1.x = f2b(b.x); o1.y = f2b(b.y); o1.z = f2b(b.z); o1.w = f2b(b.w);
  *(ushort4*)(dst + i) = o0;
  *(ushort4*)(dst + i + 4) = o1;
}

// ======== f32 split-K 128x128 GEMM, software-pipelined staging (R8-proven) ========
template<bool EXPERT>
__global__ __launch_bounds__(256) void k_skf32(
    const float* __restrict__ A, const float* __restrict__ W0,
    const float* __restrict__ W1, const float* __restrict__ W2,
    float* __restrict__ part, int M, int Ntot, int Nthird, int K, int KC,
    int nsplit, int prows,
    const int* __restrict__ counts, const int* __restrict__ bases) {
  int s, base = 0, cnt = M, sel = 0, n0;
  const float* W;
  if (EXPERT) {
    int z = blockIdx.z;
    s = z % nsplit;
    int e = z / nsplit;
    cnt = counts[e]; base = bases[e];
    W = W0 + (size_t)e * K * Nthird;
    n0 = blockIdx.x * 128;
  } else {
    s = blockIdx.z;
    int tpn = Nthird >> 7;
    sel = blockIdx.x / tpn;
    n0 = (blockIdx.x - sel * tpn) * 128;
    W = sel == 0 ? W0 : sel == 1 ? W1 : W2;
  }
  int m0 = blockIdx.y * 128;
  if (EXPERT && m0 >= cnt) return;
  int kbase = s * KC;

  __shared__ float As[16][132];   // k-major: As[k][m]
  __shared__ float Bs[16][132];
  int tid = threadIdx.x;
  int tx = tid & 15, ty = tid >> 4;
  int ra = tid >> 1, ka0 = (tid & 1) * 8;
  int kb = tid >> 4, nb0 = (tid & 15) * 8;
  bool arow_ok = !EXPERT || (m0 + ra < cnt);
  const float* Arow = A + (size_t)(EXPERT ? (base + m0 + (arow_ok ? ra : 0))
                                          : (m0 + ra)) * K + kbase;
  float acc[8][8] = {};

  float4 av0 = make_float4(0.f, 0.f, 0.f, 0.f), av1 = av0, bv0, bv1;
  if (arow_ok) {
    av0 = *(const float4*)(Arow + ka0);
    av1 = *(const float4*)(Arow + ka0 + 4);
  }
  {
    const float* Wrow = W + (size_t)(kbase + kb) * Nthird + n0 + nb0;
    bv0 = *(const float4*)(Wrow);
    bv1 = *(const float4*)(Wrow + 4);
  }

  for (int k0 = 0; k0 < KC; k0 += 16) {
    As[ka0 + 0][ra] = av0.x; As[ka0 + 1][ra] = av0.y;
    As[ka0 + 2][ra] = av0.z; As[ka0 + 3][ra] = av0.w;
    As[ka0 + 4][ra] = av1.x; As[ka0 + 5][ra] = av1.y;
    As[ka0 + 6][ra] = av1.z; As[ka0 + 7][ra] = av1.w;
    *(float4*)&Bs[kb][nb0] = bv0;
    *(float4*)&Bs[kb][nb0 + 4] = bv1;
    __syncthreads();
    float4 nav0 = make_float4(0.f, 0.f, 0.f, 0.f), nav1 = nav0, nbv0 = nav0, nbv1 = nav0;
    if (k0 + 16 < KC) {
      if (arow_ok) {
        nav0 = *(const float4*)(Arow + k0 + 16 + ka0);
        nav1 = *(const float4*)(Arow + k0 + 16 + ka0 + 4);
      }
      const float* Wn = W + (size_t)(kbase + k0 + 16 + kb) * Nthird + n0 + nb0;
      nbv0 = *(const float4*)(Wn);
      nbv1 = *(const float4*)(Wn + 4);
    }
#pragma unroll
    for (int kk = 0; kk < 16; kk++) {
      float4 a0 = *(const float4*)&As[kk][ty * 8];
      float4 a1 = *(const float4*)&As[kk][ty * 8 + 4];
      float4 b0 = *(const float4*)&Bs[kk][tx * 8];
      float4 b1 = *(const float4*)&Bs[kk][tx * 8 + 4];
      float a[8] = {a0.x, a0.y, a0.z, a0.w, a1.x, a1.y, a1.z, a1.w};
      float b[8] = {b0.x, b0.y, b0.z, b0.w, b1.x, b1.y, b1.z, b1.w};
#pragma unroll
      for (int i = 0; i < 8; i++) {
#pragma unroll
        for (int j = 0; j < 8; j++) acc[i][j] = fmaf(a[i], b[j], acc[i][j]);
      }
    }
    __syncthreads();
    av0 = nav0; av1 = nav1; bv0 = nbv0; bv1 = nbv1;
  }
#pragma unroll
  for (int i = 0; i < 8; i++) {
    int m = m0 + ty * 8 + i;
    if (EXPERT && m >= cnt) continue;
    size_t prow = EXPERT ? ((size_t)s * prows + base + m) : ((size_t)s * M + m);
    float* orow = part + prow * Ntot + sel * Nthird;
#pragma unroll
    for (int j = 0; j < 8; j++)
      orow[n0 + tx * 8 + j] = acc[i][j];
  }
}

// ---- QKV reduce: q/k/v = part0+part1 + bias ----
__global__ __launch_bounds__(256) void k_qkvred(const float* __restrict__ part,
    const float* __restrict__ bq, const float* __restrict__ bk,
    const float* __restrict__ bv, float* __restrict__ qb,
    float* __restrict__ kb, float* __restrict__ vb) {
  int t = blockIdx.x;
  for (int c = threadIdx.x; c < 2304; c += 256) {
    float v = part[(size_t)t * 2304 + c] + part[((size_t)TT + t) * 2304 + c];
    if (c < 768)       qb[(size_t)t * DD + c] = v + bq[c];
    else if (c < 1536) kb[(size_t)t * DD + c - 768] = v + bk[c - 768];
    else               vb[(size_t)t * DD + c - 1536] = v + bv[c - 1536];
  }
}

// ---------------- attention (f32); PV phase pairs qi (g, g+4) ----
__global__ __launch_bounds__(256) void k_attn(const float* __restrict__ q,
    const float* __restrict__ k, const float* __restrict__ v, float* __restrict__ ao) {
  int b = blockIdx.z, hh = blockIdx.y, q0 = blockIdx.x * QBLK;
  __shared__ float qs[QBLK][64];
  __shared__ float sc[QBLK][SS];
  __shared__ float red[QBLK][8];
  int tid = threadIdx.x;
  const size_t hoff = (size_t)b * SS * DD + (size_t)hh * 64;
  for (int i = tid; i < QBLK * 64; i += 256) {
    int qi = i >> 6, d = i & 63;
    qs[qi][d] = q[hoff + (size_t)(q0 + qi) * DD + d];
  }
  __syncthreads();
  int kmax = q0 + QBLK;
  for (int j = tid; j < kmax; j += 256) {
    const float* kr = k + hoff + (size_t)j * DD;
    float p[QBLK];
#pragma unroll
    for (int qi = 0; qi < QBLK; qi++) p[qi] = 0.f;
#pragma unroll 4
    for (int c = 0; c < 16; c++) {
      float4 kv = *(const float4*)(kr + c * 4);
#pragma unroll
      for (int qi = 0; qi < QBLK; qi++)
        p[qi] += qs[qi][c * 4] * kv.x + qs[qi][c * 4 + 1] * kv.y +
                 qs[qi][c * 4 + 2] * kv.z + qs[qi][c * 4 + 3] * kv.w;
    }
#pragma unroll
    for (int qi = 0; qi < QBLK; qi++)
      sc[qi][j] = (j <= q0 + qi) ? p[qi] * 0.125f : -1e30f;
  }
  __syncthreads();
  int wid = tid >> 6, lane = tid & 63;
#pragma unroll
  for (int qi = 0; qi < QBLK; qi++) {
    float mx = -1e30f;
    for (int j = tid; j < kmax; j += 256) mx = fmaxf(mx, sc[qi][j]);
    for (int off = 32; off > 0; off >>= 1) mx = fmaxf(mx, __shfl_down(mx, off, 64));
    if (lane == 0) red[qi][wid] = mx;
  }
  __syncthreads();
#pragma unroll
  for (int qi = 0; qi < QBLK; qi++) {
    float mx = fmaxf(fmaxf(red[qi][0], red[qi][1]), fmaxf(red[qi][2], red[qi][3]));
    float s = 0.f;
    for (int j = tid; j < kmax; j += 256) {
      float e = __expf(sc[qi][j] - mx);
      sc[qi][j] = e;
      s += e;
    }
    for (int off = 32; off > 0; off >>= 1) s += __shfl_down(s, off, 64);
    if (lane == 0) red[qi][4 + wid] = s;
  }
  __syncthreads();
  int d = tid & 63, g = tid >> 6;
  {
    int qiA = g, qiB = g + 4;
    float invA = 1.f / (red[qiA][4] + red[qiA][5] + red[qiA][6] + red[qiA][7]);
    float invB = 1.f / (red[qiB][4] + red[qiB][5] + red[qiB][6] + red[qiB][7]);
    int jendA = q0 + qiA + 1;
    int jendB = q0 + qiB + 1;
    const float* vp = v + hoff + d;
    float a0 = 0.f, a1 = 0.f, a2 = 0.f, a3 = 0.f;
    float b0 = 0.f, b1 = 0.f, b2 = 0.f, b3 = 0.f;
    int jA4 = jendA & ~3;
    for (int j = 0; j < jA4; j += 4) {
      float v0 = vp[(size_t)j * DD];
      float v1 = vp[(size_t)(j + 1) * DD];
      float v2 = vp[(size_t)(j + 2) * DD];
      float v3 = vp[(size_t)(j + 3) * DD];
      a0 = fmaf(sc[qiA][j],     v0, a0);
      a1 = fmaf(sc[qiA][j + 1], v1, a1);
      a2 = fmaf(sc[qiA][j + 2], v2, a2);
      a3 = fmaf(sc[qiA][j + 3], v3, a3);
      b0 = fmaf(sc[qiB][j],     v0, b0);
      b1 = fmaf(sc[qiB][j + 1], v1, b1);
      b2 = fmaf(sc[qiB][j + 2], v2, b2);
      b3 = fmaf(sc[qiB][j + 3], v3, b3);
    }
    for (int t = jA4; t < jendA; t++)
      a0 = fmaf(sc[qiA][t], vp[(size_t)t * DD], a0);
    b0 = fmaf(sc[qiB][jA4],     vp[(size_t)jA4 * DD], b0);
    b1 = fmaf(sc[qiB][jA4 + 1], vp[(size_t)(jA4 + 1) * DD], b1);
    b2 = fmaf(sc[qiB][jA4 + 2], vp[(size_t)(jA4 + 2) * DD], b2);
    b3 = fmaf(sc[qiB][jA4 + 3], vp[(size_t)(jA4 + 3) * DD], b3);
    for (int t = jA4 + 4; t < jendB; t++)
      b0 = fmaf(sc[qiB][t], vp[(size_t)t * DD], b0);
    float accA = (a0 + a2) + (a1 + a3);
    float accB = (b0 + b2) + (b1 + b3);
    ao[hoff + (size_t)(q0 + qiA) * DD + d] = accA * invA;
    ao[hoff + (size_t)(q0 + qiB) * DD + d] = accB * invB;
  }
}

// ---- fused router: top2 + LDS histogram + scan + assign (1 block) ----
// gtok permutation depends on LDS-atomic order, but downstream results are
// row-order invariant (per-row GEMM + indexed gather-back) -> output identical.
__global__ __launch_bounds__(1024) void k_route(const float* __restrict__ glog,
    int* __restrict__ tidx, float* __restrict__ tw, int* __restrict__ rows,
    int* __restrict__ gtok, int* __restrict__ counts, int* __restrict__ bases) {
  __shared__ int cnt_s[EE], base_s[EE], cur_s[EE];
  int tid = threadIdx.x;
  if (tid < EE) cnt_s[tid] = 0;
  __syncthreads();
  for (int t = tid; t < TT; t += 1024) {
    float l[EE];
#pragma unroll
    for (int e = 0; e < EE; e++) l[e] = glog[t * EE + e];
    int i0 = 0; float v0 = l[0];
#pragma unroll
    for (int e = 1; e < EE; e++) if (l[e] > v0) { v0 = l[e]; i0 = e; }
    int i1 = -1; float v1 = -1e30f;
#pragma unroll
    for (int e = 0; e < EE; e++) if (e != i0 && l[e] > v1) { v1 = l[e]; i1 = e; }
    float e1 = __expf(v1 - v0);
    float inv = 1.f / (1.f + e1);
    tw[t * 2] = inv; tw[t * 2 + 1] = e1 * inv;
    tidx[t * 2] = i0; tidx[t * 2 + 1] = i1;
    atomicAdd(&cnt_s[i0], 1);
    atomicAdd(&cnt_s[i1], 1);
  }
  __syncthreads();
  if (tid == 0) {
    int b = 0;
    for (int e = 0; e < EE; e++) { base_s[e] = b; cur_s[e] = b; b += cnt_s[e]; }
  }
  __syncthreads();
  for (int t = tid; t < TT; t += 1024) {
#pragma unroll
    for (int kk = 0; kk < 2; kk++) {
      int e = tidx[t * 2 + kk];
      int r = atomicAdd(&cur_s[e], 1);
      rows[t * 2 + kk] = r;
      gtok[r] = t;
    }
  }
  __syncthreads();
  if (tid < EE) { counts[tid] = cnt_s[tid]; bases[tid] = base_s[tid]; }
}

// ------- f32 expert FFN1, pipelined staging (R8-proven, feeds router) -------
__global__ __launch_bounds__(256) void k_expert1(const float* __restrict__ h,
    const float* __restrict__ w1, const float* __restrict__ b1,
    const int* __restrict__ gtok, const int* __restrict__ counts,
    const int* __restrict__ bases, float* __restrict__ gh1) {
  int e = blockIdx.z;
  int cnt = counts[e];
  int m0 = blockIdx.y * 128;
  if (m0 >= cnt) return;
  int base = bases[e];
  int n0 = blockIdx.x * 128;
  const float* W = w1 + (size_t)e * DD * FF;
  __shared__ float As[16][132];   // k-major
  __shared__ float Bs[16][132];
  int tid = threadIdx.x;
  int tx = tid & 15, ty = tid >> 4;
  int ra = tid >> 1, ka0 = (tid & 1) * 8;
  int kb = tid >> 4, nb0 = (tid & 15) * 8;
  int tok = (m0 + ra < cnt) ? gtok[base + m0 + ra] : -1;
  const float* Arow = h + (size_t)(tok < 0 ? 0 : tok) * DD;
  float acc[8][8] = {};

  float4 av0 = make_float4(0.f, 0.f, 0.f, 0.f), av1 = av0, bv0, bv1;
  if (tok >= 0) {
    av0 = *(const float4*)(Arow + ka0);
    av1 = *(const float4*)(Arow + ka0 + 4);
  }
  {
    const float* Wrow = W + (size_t)kb * FF + n0 + nb0;
    bv0 = *(const float4*)(Wrow);
    bv1 = *(const float4*)(Wrow + 4);
  }

  for (int k0 = 0; k0 < DD; k0 += 16) {
    As[ka0 + 0][ra] = av0.x; As[ka0 + 1][ra] = av0.y;
    As[ka0 + 2][ra] = av0.z; As[ka0 + 3][ra] = av0.w;
    As[ka0 + 4][ra] = av1.x; As[ka0 + 5][ra] = av1.y;
    As[ka0 + 6][ra] = av1.z; As[ka0 + 7][ra] = av1.w;
    *(float4*)&Bs[kb][nb0] = bv0;
    *(float4*)&Bs[kb][nb0 + 4] = bv1;
    __syncthreads();
    float4 nav0 = make_float4(0.f, 0.f, 0.f, 0.f), nav1 = nav0, nbv0 = nav0, nbv1 = nav0;
    if (k0 + 16 < DD) {
      if (tok >= 0) {
        nav0 = *(const float4*)(Arow + k0 + 16 + ka0);
        nav1 = *(const float4*)(Arow + k0 + 16 + ka0 + 4);
      }
      const float* Wn = W + (size_t)(k0 + 16 + kb) * FF + n0 + nb0;
      nbv0 = *(const float4*)(Wn);
      nbv1 = *(const float4*)(Wn + 4);
    }
#pragma unroll
    for (int kk = 0; kk < 16; kk++) {
      float4 a0 = *(const float4*)&As[kk][ty * 8];
      float4 a1 = *(const float4*)&As[kk][ty * 8 + 4];
      float4 b0 = *(const float4*)&Bs[kk][tx * 8];
      float4 b1 = *(const float4*)&Bs[kk][tx * 8 + 4];
      float a[8] = {a0.x, a0.y, a0.z, a0.w, a1.x, a1.y, a1.z, a1.w};
      float b[8] = {b0.x, b0.y, b0.z, b0.w, b1.x, b1.y, b1.z, b1.w};
#pragma unroll
      for (int i = 0; i < 8; i++) {
#pragma unroll
        for (int j = 0; j < 8; j++) acc[i][j] = fmaf(a[i], b[j], acc[i][j]);
      }
    }
    __syncthreads();
    av0 = nav0; av1 = nav1; bv0 = nbv0; bv1 = nbv1;
  }
#pragma unroll
  for (int i = 0; i < 8; i++) {
    int m = m0 + ty * 8 + i;
    if (m >= cnt) continue;
    float* orow = gh1 + (size_t)(base + m) * FF;
#pragma unroll
    for (int j = 0; j < 8; j++) {
      int n = n0 + tx * 8 + j;
      float vv = acc[i][j] + b1[e * FF + n];
      orow[n] = 0.5f * vv * (1.f + erff(vv * 0.70710678118654752f));
    }
  }
}

// ===== bf16 MFMA GEMM, m97-style global_load_lds staging (linear LDS) =====
template<bool EXPERT, bool GATHER, bool BIAS, int EPI>
__global__ __launch_bounds__(256) void k_mfma2(
    const unsigned short* __restrict__ A, const unsigned short* __restrict__ Bt,
    const float* __restrict__ bias, void* __restrict__ Cv,
    int M, int N, int K,
    const int* __restrict__ gtok, const int* __restrict__ counts,
    const int* __restrict__ bases) {
  int cnt = M, base = 0;
  if (EXPERT) {
    int e = blockIdx.z;
    cnt = counts[e]; base = bases[e];
    if (BIAS) bias += (size_t)e * N;
    Bt += (size_t)e * N * K;
  }
  int m0 = blockIdx.y * 128;
  if (EXPERT && m0 >= cnt) return;
  int n0 = blockIdx.x * 128;

  __shared__ unsigned short As[128 * 32];
  __shared__ unsigned short Bs[128 * 32];

  int tid = threadIdx.x, lane = tid & 63, w = tid >> 6;
  int r0 = w * 16 + (lane >> 2);
  int r1 = 64 + r0;
  int kc = (lane & 3) * 8;

  const unsigned short *pA0, *pA1;
  if (GATHER) {
    int t0 = (m0 + r0 < cnt) ? gtok[base + m0 + r0] : 0;
    int t1 = (m0 + r1 < cnt) ? gtok[base + m0 + r1] : 0;
    pA0 = A + (size_t)t0 * K + kc;
    pA1 = A + (size_t)t1 * K + kc;
  } else if (EXPERT) {
    int q0_ = (m0 + r0 < cnt) ? base + m0 + r0 : base;
    int q1_ = (m0 + r1 < cnt) ? base + m0 + r1 : base;
    pA0 = A + (size_t)q0_ * K + kc;
    pA1 = A + (size_t)q1_ * K + kc;
  } else {
    pA0 = A + (size_t)(m0 + r0) * K + kc;
    pA1 = A + (size_t)(m0 + r1) * K + kc;
  }
  const unsigned short* pB0 = Bt + (size_t)(n0 + r0) * K + kc;
  const unsigned short* pB1 = Bt + (size_t)(n0 + r1) * K + kc;

  unsigned short* dA0 = As + w * 512;
  unsigned short* dA1 = As + 2048 + w * 512;
  unsigned short* dB0 = Bs + w * 512;
  unsigned short* dB1 = Bs + 2048 + w * 512;

  int wr = w >> 1, wc = w & 1;
  int l15 = lane & 15, lg = lane >> 4;
  const unsigned short* Ar = As + ((wr * 64 + l15) * 32 + lg * 8);
  const unsigned short* Br = Bs + ((wc * 64 + l15) * 32 + lg * 8);

  f32x4 acc[4][4];
#pragma unroll
  for (int i = 0; i < 4; i++)
#pragma unroll
    for (int j = 0; j < 4; j++) acc[i][j] = (f32x4){0.f, 0.f, 0.f, 0.f};

  for (int k0 = 0; k0 < K; k0 += 32) {
    GL16(dA0, pA0 + k0);
    GL16(dA1, pA1 + k0);
    GL16(dB0, pB0 + k0);
    GL16(dB1, pB1 + k0);
    __syncthreads();
    bf16x8 af[4], bfr[4];
#pragma unroll
    for (int f = 0; f < 4; f++) {
      af[f]  = *(const bf16x8*)(Ar + f * 512);
      bfr[f] = *(const bf16x8*)(Br + f * 512);
    }
#pragma unroll
    for (int i = 0; i < 4; i++)
#pragma unroll
      for (int j = 0; j < 4; j++)
        acc[i][j] = __builtin_amdgcn_mfma_f32_16x16x32_bf16(af[i], bfr[j], acc[i][j], 0, 0, 0);
    __syncthreads();
  }

#pragma unroll
  for (int j = 0; j < 4; j++) {
    int n = n0 + wc * 64 + j * 16 + l15;
    float bb = BIAS ? bias[n] : 0.f;
#pragma unroll
    for (int i = 0; i < 4; i++) {
      int mb = m0 + wr * 64 + i * 16 + lg * 4;
#pragma unroll
      for (int r = 0; r < 4; r++) {
        int m = mb + r;
        if (EXPERT && m >= cnt) continue;
        size_t off = (size_t)(base + m) * N + n;
        float v = acc[i][j][r] + bb;
        if (EPI == 0) {
          ((float*)Cv)[off] = v;
        } else {
          float g = 0.5f * v * (1.f + erff(v * 0.70710678118654752f));
          ((unsigned short*)Cv)[off] = f2b(g);
        }
      }
    }
  }
}

// ===== bf16 MFMA GEMM, register-staged, B from f32 (lm_head tail tiles) =====
__global__ __launch_bounds__(256) void k_mfma_bf32(
    const unsigned short* __restrict__ A, const float* __restrict__ Bf,
    float* __restrict__ C, int M, int N, int K, int mtile0) {
  int m0 = (blockIdx.y + mtile0) * 128;
  int n0 = blockIdx.x * 128;
  __shared__ unsigned short As[128 * 40];
  __shared__ unsigned short Bs[128 * 40];
  int tid = threadIdx.x;
  int srow = tid >> 1;
  int scol = (tid & 1) * 16;
  const unsigned short* arow = A + (size_t)(m0 + srow) * K + scol;
  const float* browf = Bf + (size_t)(n0 + srow) * K + scol;
  unsigned short* As_w = As + srow * 40 + scol;
  unsigned short* Bs_w = Bs + srow * 40 + scol;
  int lane = tid & 63, wid = tid >> 6;
  int wr = wid >> 1, wc = wid & 1;
  int l15 = lane & 15, lg = lane >> 4;
  const unsigned short* Ar = As + ((wr * 64 + l15) * 40 + lg * 8);
  const unsigned short* Br = Bs + ((wc * 64 + l15) * 40 + lg * 8);
  f32x4 acc[4][4];
#pragma unroll
  for (int i = 0; i < 4; i++)
#pragma unroll
    for (int j = 0; j < 4; j++) acc[i][j] = (f32x4){0.f, 0.f, 0.f, 0.f};
  for (int k0 = 0; k0 < K; k0 += 32) {
    uint4 av0 = *(const uint4*)(arow + k0);
    uint4 av1 = *(const uint4*)(arow + k0 + 8);
    float4 f0 = *(const float4*)(browf + k0);
    float4 f1 = *(const float4*)(browf + k0 + 4);
    float4 f2 = *(const float4*)(browf + k0 + 8);
    float4 f3 = *(const float4*)(browf + k0 + 12);
    uint4 bv0 = make_uint4(pk2(f0.x, f0.y), pk2(f0.z, f0.w), pk2(f1.x, f1.y), pk2(f1.z, f1.w));
    uint4 bv1 = make_uint4(pk2(f2.x, f2.y), pk2(f2.z, f2.w), pk2(f3.x, f3.y), pk2(f3.z, f3.w));
    *(uint4*)As_w = av0; *(uint4*)(As_w + 8) = av1;
    *(uint4*)Bs_w = bv0; *(uint4*)(Bs_w + 8) = bv1;
    __syncthreads();
    bf16x8 af[4], bfr[4];
#pragma unroll
    for (int f = 0; f < 4; f++) {
      af[f]  = *(const bf16x8*)(Ar + f * 640);
      bfr[f] = *(const bf16x8*)(Br + f * 640);
    }
#pragma unroll
    for (int i = 0; i < 4; i++)
#pragma unroll
      for (int j = 0; j < 4; j++)
        acc[i][j] = __builtin_amdgcn_mfma_f32_16x16x32_bf16(af[i], bfr[j], acc[i][j], 0, 0, 0);
    __syncthreads();
  }
#pragma unroll
  for (int j = 0; j < 4; j++) {
    int n = n0 + wc * 64 + j * 16 + l15;
#pragma unroll
    for (int i = 0; i < 4; i++) {
      int mb = m0 + wr * 64 + i * 16 + lg * 4;
#pragma unroll
      for (int r = 0; r < 4; r++)
        C[(size_t)(mb + r) * N + n] = acc[i][j][r];
    }
  }
}

// ================= host =================
extern "C" void kernel_launch(void* const* d_in, const int* in_sizes, int n_in,
                              void* d_out, int out_size, void* d_ws, size_t ws_size,
                              hipStream_t stream) {
  (void)in_sizes; (void)n_in; (void)out_size;
  const int* tok   = (const int*)d_in[0];
  const float* emb = (const float*)d_in[1];
  const float* pos = (const float*)d_in[2];
  const float* wq  = (const float*)d_in[3];
  const float* bq  = (const float*)d_in[4];
  const float* wk  = (const float*)d_in[5];
  const float* bk  = (const float*)d_in[6];
  const float* wv  = (const float*)d_in[7];
  const float* bvv = (const float*)d_in[8];
  const float* wo  = (const float*)d_in[9];
  const float* bo  = (const float*)d_in[10];
  const float* ln1 = (const float*)d_in[11];
  const float* ln2 = (const float*)d_in[12];
  const float* gw  = (const float*)d_in[13];
  const float* gb  = (const float*)d_in[14];
  const float* w1  = (const float*)d_in[15];
  const float* b1  = (const float*)d_in[16];
  const float* w2  = (const float*)d_in[17];
  const float* b2  = (const float*)d_in[18];
  const float* lnf = (const float*)d_in[19];

  // ---- scratch carved from d_out (65.5M f32; all dead before lm_head) ----
  float* ob = (float*)d_out;
  float* fp = ob;
  float* qb   = fp; fp += (size_t)TT * DD;
  float* kb   = fp; fp += (size_t)TT * DD;
  float* vb   = fp; fp += (size_t)TT * DD;
  float* ao   = fp; fp += (size_t)TT * DD;
  float* x    = fp; fp += (size_t)TT * DD;
  float* h    = fp; fp += (size_t)TT * DD;
  float* gh1  = fp; fp += (size_t)TT * 2 * FF;
  float* go   = fp; fp += (size_t)TT * 2 * DD;
  float* glog = fp; fp += (size_t)TT * EE;
  float* tw   = fp; fp += (size_t)TT * 2;
  int* tidx   = (int*)fp; fp += TT * 2;
  int* rows   = (int*)fp; fp += TT * 2;
  int* gtok   = (int*)fp; fp += TT * 2;
  int* counts = (int*)fp; fp += 16;
  int* cursor = (int*)fp; fp += 16;
  int* bases  = (int*)fp; fp += 16;
  unsigned short* hb   = (unsigned short*)fp; fp += (size_t)TT * DD / 2;
  unsigned short* gh1b = (unsigned short*)fp; fp += (size_t)TT * 2 * FF / 2;
  unsigned short* w1t  = (unsigned short*)fp; fp += (size_t)EE * DD * FF / 2;
  unsigned short* w2t  = (unsigned short*)fp; fp += (size_t)EE * FF * DD / 2;
  float* part = fp; fp += (size_t)4 * 4096 * DD;
  (void)cursor;

  unsigned short* hf = (unsigned short*)d_ws;
  bool useWs = ws_size >= (size_t)TT * DD * 2 + (size_t)VV * DD * 2;
  unsigned short* embT = useWs ? (unsigned short*)d_ws + (size_t)TT * DD
                               : (unsigned short*)(ob + 53248000ull);

  // ---- pre-pass ----
  k_embed_rms<<<TT, 256, 0, stream>>>(tok, emb, pos, ln1, x, h, hb);
  k_tcvt<<<dim3(96, 24, EE), 256, 0, stream>>>(w1 + (size_t)1 * EE * DD * FF, w1t,
      DD, FF, (size_t)DD * FF, (size_t)DD * FF);
  k_tcvt<<<dim3(24, 96, EE), 256, 0, stream>>>(w2 + (size_t)1 * EE * FF * DD, w2t,
      FF, DD, (size_t)FF * DD, (size_t)FF * DD);

  for (int l = 0; l < NLAYER; l++) {
    const float* wq_l = wq + (size_t)l * DD * DD;
    const float* wk_l = wk + (size_t)l * DD * DD;
    const float* wv_l = wv + (size_t)l * DD * DD;
    const float* wo_l = wo + (size_t)l * DD * DD;

    // attention block (f32 — feeds routers); h/hb already prepared
    k_skf32<false><<<dim3(18, 16, 2), 256, 0, stream>>>(h, wq_l, wk_l, wv_l,
        part, TT, 2304, 768, 768, 384, 2, TT, nullptr, nullptr);
    k_qkvred<<<TT, 256, 0, stream>>>(part, bq + (size_t)l * DD, bk + (size_t)l * DD,
        bvv + (size_t)l * DD, qb, kb, vb);
    k_attn<<<dim3(SS / QBLK, HH, BB), 256, 0, stream>>>(qb, kb, vb, ao);
    k_skf32<false><<<dim3(6, 16, 4), 256, 0, stream>>>(ao, wo_l, wo_l, wo_l,
        part, TT, 768, 768, 768, 192, 4, TT, nullptr, nullptr);
    // O-reduce + residual + rmsnorm(ln2) + gate (fused)
    k_ored_rms_gate<<<TT, 256, 0, stream>>>(part, bo + (size_t)l * DD,
        ln2 + (size_t)l * DD, gw + (size_t)l * DD * EE, gb + (size_t)l * EE,
        x, h, hb, glog);
    k_route<<<1, 1024, 0, stream>>>(glog, tidx, tw, rows, gtok, counts, bases);
    if (l < NLAYER - 1) {
      k_expert1<<<dim3(FF / 128, TT / 128, EE), 256, 0, stream>>>(
          h, w1 + (size_t)l * EE * DD * FF, b1 + (size_t)l * EE * FF,
          gtok, counts, bases, gh1);
      k_skf32<true><<<dim3(6, 16, 32), 256, 0, stream>>>(gh1,
          w2 + (size_t)l * EE * FF * DD, nullptr, nullptr,
          part, TT, 768, 768, FF, 768, 4, 4096, counts, bases);
      // expert2-reduce + scatter + rmsnorm(ln1 of next layer) (fused)
      k_e2red_rms<<<TT, 256, 0, stream>>>(part, rows, tidx, tw,
          b2 + (size_t)l * EE * DD, ln1 + (size_t)(l + 1) * DD, x, h, hb);
    } else {
      k_mfma2<true, true, true, 2><<<dim3(FF / 128, TT / 128, EE), 256, 0, stream>>>(
          hb, w1t, b1 + (size_t)l * EE * FF, gh1b,
          TT, FF, DD, gtok, counts, bases);
      k_mfma2<true, false, true, 0><<<dim3(DD / 128, TT / 128, EE), 256, 0, stream>>>(
          gh1b, w2t, b2 + (size_t)l * EE * DD, go,
          TT, DD, FF, gtok, counts, bases);
      // scatter + rmsnorm(lnf) -> hf (fused)
      k_scatter_rms<<<TT, 256, 0, stream>>>(go, rows, tw, lnf, x, hf);
    }
  }

  // embT conversion (arena tail is dead now) + lm_head
  k_cvt<<<(VV * DD) / (256 * 8), 256, 0, stream>>>(emb, embT);
  if (useWs) {
    k_mfma2<false, false, false, 0><<<dim3(VV / 128, 16), 256, 0, stream>>>(
        hf, embT, nullptr, (float*)d_out,
        TT, VV, DD, nullptr, nullptr, nullptr);
  } else {
    k_mfma2<false, false, false, 0><<<dim3(VV / 128, 13), 256, 0, stream>>>(
        hf, embT, nullptr, (float*)d_out,
        TT, VV, DD, nullptr, nullptr, nullptr);
    k_mfma_bf32<<<dim3(VV / 128, 3), 256, 0, stream>>>(
        hf, emb, (float*)d_out, TT, VV, DD, 13);
  }
}